// Round 9
// baseline (1826.084 us; speedup 1.0000x reference)
//
#include <hip/hip_runtime.h>
#include <cstdint>
#include <cstddef>

#define NEG_SLOPE 0.2f
#define GRID 1024
#define NTHR 256

__device__ __forceinline__ float elu_f(float x) {
    return x > 0.f ? x : expm1f(x);
}

// Device-scope soft grid barrier: fresh counter word per barrier (init-zeroed),
// arrive via atomicAdd after __threadfence (release), spin with atomic reads,
// __threadfence after (invalidates L1 so post-barrier loads see fresh data).
__device__ __forceinline__ void gbar(int* bar, int idx) {
    __syncthreads();
    if (threadIdx.x == 0) {
        __threadfence();
        atomicAdd(&bar[idx], 1);
        while (atomicAdd(&bar[idx], 0) < GRID) __builtin_amdgcn_s_sleep(2);
    }
    __syncthreads();
    __threadfence();
}

__global__ void init_kernel(int* bar) {
    if (threadIdx.x < 16) bar[threadIdx.x] = 0;
}

// ---------------------------------------------------------------------------
// Persistent mega-kernel: CSR build + fold + encoder + 3x(agg, post) + MLP.
// 1024 blocks x 256 thr, 4 blocks/CU co-resident (launch_bounds + LDS<=40KB).
// ---------------------------------------------------------------------------
#define H1STR 68
__global__ __launch_bounds__(256, 4) void mega_kernel(
    const float* __restrict__ x, const int* __restrict__ ei,
    const float* __restrict__ Wenc1, const float* __restrict__ benc1,
    const float* __restrict__ Wenc2, const float* __restrict__ benc2,
    const float* __restrict__ Wg0, const float* __restrict__ as0,
    const float* __restrict__ ad0, const float* __restrict__ bg0,
    const float* __restrict__ Wg1, const float* __restrict__ as1,
    const float* __restrict__ ad1, const float* __restrict__ bg1,
    const float* __restrict__ Wg2, const float* __restrict__ as2,
    const float* __restrict__ ad2, const float* __restrict__ bg2,
    const float* __restrict__ Wm1, const float* __restrict__ bm1,
    const float* __restrict__ Wm2, const float* __restrict__ bm2,
    const float* __restrict__ Wm3, const float* __restrict__ bm3,
    float* buf0, float* buf1, float* g, float* asrc, float* adst, float* vfold,
    int* rowptr, int* cursor, int* cnt, int* ready, int* flag, int* col,
    int* bar, float* outp, int N, int E) {

    __shared__ float S[9984];   // 39,936 B; carved per phase
    const int t = threadIdx.x, b = blockIdx.x;
    const int Etot = E + N;

    // ======== P0: zero cnt/ready, detect layout, fold attention vectors ====
    for (int i = b * NTHR + t; i < N; i += GRID * NTHR) cnt[i] = 0;
    if (b == 0) {
        if (t < 128) ready[t] = 0;
        if (t == 0) {
            int acc = 0;
#pragma unroll
            for (int k = 0; k < 8; ++k) acc |= ei[2 * k + 1];
            flag[0] = (acc == 0) ? 1 : 0;
        }
    }
    if (b >= 1 && b <= 6) {
        const int e = (b - 1) * NTHR + t;
        if (e < 1536) {
            const int l = e >> 9, rem = e & 511;
            const int k = rem >> 3, j = rem & 7, h = j & 3;
            const float* W   = (l == 0) ? Wg0 : (l == 1) ? Wg1 : Wg2;
            const float* asl = (l == 0) ? as0 : (l == 1) ? as1 : as2;
            const float* adl = (l == 0) ? ad0 : (l == 1) ? ad1 : ad2;
            const float* av = (j < 4) ? asl : adl;
            const float* wr = W + k * 256 + h * 64;
            const float* ar = av + h * 64;
            float s = 0.f;
#pragma unroll 8
            for (int cc = 0; cc < 64; ++cc) s += wr[cc] * ar[cc];
            vfold[l * 512 + k * 8 + j] = s;
        }
    }
    gbar(bar, 0);

    // ======== P1: count degrees ========
    {
        const int isI64 = flag[0];
        for (int e = b * NTHR + t; e < Etot; e += GRID * NTHR) {
            int d;
            if (e < E) d = isI64 ? ei[2 * (size_t)(E + e)] : ei[E + e];
            else       d = e - E;
            atomicAdd(&cnt[d], 1);
        }
    }
    gbar(bar, 1);

    // ======== P2: scan with lookback (blocks 0..nchunk-1) ========
    {
        const int nchunk = (N + 255) >> 8;
        if (b < nchunk) {
            int* sd   = (int*)S;       // 256
            int* sred = sd + 256;      // 128
            int* sprf = sd + 400;      // 1
            const int gi = b * 256 + t;
            const int v = (gi < N) ? cnt[gi] : 0;
            sd[t] = v;
            __syncthreads();
            for (int off = 1; off < 256; off <<= 1) {
                int add = (t >= off) ? sd[t - off] : 0;
                __syncthreads();
                sd[t] += add;
                __syncthreads();
            }
            if (t == 255) atomicExch(&ready[b], sd[255] + 1);
            if (t < 128) {
                int pv = 0;
                if (t < b) {
                    do { pv = atomicAdd(&ready[t], 0); __builtin_amdgcn_s_sleep(1); } while (pv == 0);
                    pv -= 1;
                }
                sred[t] = pv;
            }
            __syncthreads();
            if (t == 0) {
                int s = 0;
#pragma unroll 8
                for (int i = 0; i < 128; ++i) s += sred[i];
                sprf[0] = s;
            }
            __syncthreads();
            const int pre = sprf[0];
            if (gi < N) {
                const int e = pre + sd[t];
                rowptr[gi + 1] = e;
                cursor[gi] = e - v;
                if (gi == 0) rowptr[0] = 0;
            }
        }
    }
    gbar(bar, 2);

    // ======== P3: fill CSR col ========
    {
        const int isI64 = flag[0];
        for (int e = b * NTHR + t; e < Etot; e += GRID * NTHR) {
            int s, d;
            if (e < E) {
                if (isI64) { s = ei[2 * (size_t)e]; d = ei[2 * (size_t)(E + e)]; }
                else       { s = ei[e];             d = ei[E + e]; }
            } else {
                s = d = e - E;
            }
            int pos = atomicAdd(&cursor[d], 1);
            col[pos] = s;
        }
    }
    gbar(bar, 3);

    // ======== P4: encoder + layer-0 dots (64-node tiles) ========
    {
        float* W1s = S;          // 256
        float* b1s = S + 256;    // 32
        float* b2s = S + 288;    // 64
        float* vsd = S + 352;    // 512
        float* xS  = S + 864;    // 512
        float* W2s = S + 1376;   // 2048
        float* h1T = S + 3424;   // 32*68 = 2176
        const int ntile = (N + 63) >> 6;
        for (int tile = b; tile < ntile; tile += GRID) {
            const int n0 = tile * 64;
            const int rem = N - n0;
            __syncthreads();
            *(float4*)(W2s + t * 4) = *(const float4*)(Wenc2 + t * 4);
            *(float4*)(W2s + 1024 + t * 4) = *(const float4*)(Wenc2 + 1024 + t * 4);
            if (t < 64)  *(float4*)(W1s + t * 4) = *(const float4*)(Wenc1 + t * 4);
            if (t < 8)   *(float4*)(b1s + t * 4) = *(const float4*)(benc1 + t * 4);
            if (t < 16)  *(float4*)(b2s + t * 4) = *(const float4*)(benc2 + t * 4);
            if (t < 128) *(float4*)(vsd + t * 4) = *(const float4*)(vfold + t * 4);
            if (t < 128) {
                const int fidx = t * 4;
                float4 v = make_float4(0.f, 0.f, 0.f, 0.f);
                if (fidx < rem * 8) v = *(const float4*)(x + (size_t)n0 * 8 + fidx);
                *(float4*)(xS + fidx) = v;
            }
            __syncthreads();
            {   // phase A: h1 = elu(x@W1+b1) -> h1T
                const int nl = t >> 2;
                const int j0 = (t & 3) * 8;
                const float4 xa = *(const float4*)(xS + nl * 8);
                const float4 xb = *(const float4*)(xS + nl * 8 + 4);
                const float xk[8] = {xa.x, xa.y, xa.z, xa.w, xb.x, xb.y, xb.z, xb.w};
                float a[8];
#pragma unroll
                for (int u = 0; u < 8; ++u) a[u] = b1s[j0 + u];
#pragma unroll
                for (int k = 0; k < 8; ++k) {
                    const float4 w0 = *(const float4*)(W1s + k * 32 + j0);
                    const float4 w1 = *(const float4*)(W1s + k * 32 + j0 + 4);
                    a[0] += xk[k] * w0.x; a[1] += xk[k] * w0.y;
                    a[2] += xk[k] * w0.z; a[3] += xk[k] * w0.w;
                    a[4] += xk[k] * w1.x; a[5] += xk[k] * w1.y;
                    a[6] += xk[k] * w1.z; a[7] += xk[k] * w1.w;
                }
#pragma unroll
                for (int u = 0; u < 8; ++u) h1T[(j0 + u) * H1STR + nl] = elu_f(a[u]);
            }
            __syncthreads();
            {   // phase B: h0 = elu(h1@W2+b2) + fused dots
                const int cg = t & 15;
                const int nq = t >> 4;
                const int c0 = cg * 4;
                float acc[4][4];
#pragma unroll
                for (int i = 0; i < 4; ++i)
#pragma unroll
                    for (int c = 0; c < 4; ++c) acc[i][c] = b2s[c0 + c];
#pragma unroll 8
                for (int k = 0; k < 32; ++k) {
                    const float4 hv = *(const float4*)(h1T + k * H1STR + nq * 4);
                    const float4 wv = *(const float4*)(W2s + k * 64 + c0);
                    const float hvv[4] = {hv.x, hv.y, hv.z, hv.w};
#pragma unroll
                    for (int i = 0; i < 4; ++i) {
                        acc[i][0] += hvv[i] * wv.x; acc[i][1] += hvv[i] * wv.y;
                        acc[i][2] += hvv[i] * wv.z; acc[i][3] += hvv[i] * wv.w;
                    }
                }
                float o[4][4];
#pragma unroll
                for (int i = 0; i < 4; ++i)
#pragma unroll
                    for (int c = 0; c < 4; ++c) o[i][c] = elu_f(acc[i][c]);
#pragma unroll
                for (int i = 0; i < 4; ++i) {
                    const int n = n0 + nq * 4 + i;
                    if (n < N)
                        *(float4*)(buf0 + (size_t)n * 64 + c0) =
                            make_float4(o[i][0], o[i][1], o[i][2], o[i][3]);
                }
                float ad[4][8];
#pragma unroll
                for (int i = 0; i < 4; ++i)
#pragma unroll
                    for (int jj = 0; jj < 8; ++jj) ad[i][jj] = 0.f;
#pragma unroll
                for (int c = 0; c < 4; ++c) {
                    const float4 v0 = *(const float4*)(vsd + (c0 + c) * 8);
                    const float4 v1 = *(const float4*)(vsd + (c0 + c) * 8 + 4);
#pragma unroll
                    for (int i = 0; i < 4; ++i) {
                        ad[i][0] += o[i][c] * v0.x; ad[i][1] += o[i][c] * v0.y;
                        ad[i][2] += o[i][c] * v0.z; ad[i][3] += o[i][c] * v0.w;
                        ad[i][4] += o[i][c] * v1.x; ad[i][5] += o[i][c] * v1.y;
                        ad[i][6] += o[i][c] * v1.z; ad[i][7] += o[i][c] * v1.w;
                    }
                }
#pragma unroll
                for (int off = 1; off < 16; off <<= 1) {
#pragma unroll
                    for (int i = 0; i < 4; ++i)
#pragma unroll
                        for (int jj = 0; jj < 8; ++jj)
                            ad[i][jj] += __shfl_xor(ad[i][jj], off);
                }
                if (cg == 0) {
#pragma unroll
                    for (int i = 0; i < 4; ++i) {
                        const int n = n0 + nq * 4 + i;
                        if (n < N) {
#pragma unroll
                            for (int h = 0; h < 4; ++h) {
                                asrc[n * 4 + h] = ad[i][h];
                                adst[n * 4 + h] = ad[i][4 + h];
                            }
                        }
                    }
                }
            }
        }
    }
    gbar(bar, 4);

    // ======== 3 GAT layers ========
    for (int l = 0; l < 3; ++l) {
        const float* W    = (l == 0) ? Wg0 : (l == 1) ? Wg1 : Wg2;
        const float* bias = (l == 0) ? bg0 : (l == 1) ? bg1 : bg2;
        float* bin  = (l & 1) ? buf1 : buf0;
        float* bout = (l & 1) ? buf0 : buf1;
        const int has_next = (l < 2) ? 1 : 0;
        const float* vnext = vfold + (l + 1) * 512;  // only deref'd if has_next

        // ---- agg: 16-lane group per dst node ----
        {
            const int nchunk16 = (N + 15) >> 4;
            const int grp = t >> 4;
            const int q = t & 15;
            for (int chunk = b; chunk < nchunk16; chunk += GRID) {
                const int n = chunk * 16 + grp;
                if (n >= N) continue;
                const float4 ad4 = *(const float4*)(adst + (size_t)n * 4);
                const int start = rowptr[n], end = rowptr[n + 1];
                float acc[4][4];
#pragma unroll
                for (int h = 0; h < 4; ++h)
#pragma unroll
                    for (int z = 0; z < 4; ++z) acc[h][z] = 0.f;
                float4 den4 = make_float4(0.f, 0.f, 0.f, 0.f);
                for (int base = start; base < end; base += 16) {
                    const int cnt2 = min(16, end - base);
                    int c = 0;
                    float4 w4 = make_float4(0.f, 0.f, 0.f, 0.f);
                    if (base + q < end) {
                        c = col[base + q];
                        const float4 av = *(const float4*)(asrc + (size_t)c * 4);
                        float l0 = av.x + ad4.x; l0 = l0 > 0.f ? l0 : NEG_SLOPE * l0;
                        float l1 = av.y + ad4.y; l1 = l1 > 0.f ? l1 : NEG_SLOPE * l1;
                        float l2 = av.z + ad4.z; l2 = l2 > 0.f ? l2 : NEG_SLOPE * l2;
                        float l3 = av.w + ad4.w; l3 = l3 > 0.f ? l3 : NEG_SLOPE * l3;
                        w4.x = __expf(fminf(l0, 60.f));
                        w4.y = __expf(fminf(l1, 60.f));
                        w4.z = __expf(fminf(l2, 60.f));
                        w4.w = __expf(fminf(l3, 60.f));
                        den4.x += w4.x; den4.y += w4.y; den4.z += w4.z; den4.w += w4.w;
                    }
                    for (int j = 0; j < cnt2; ++j) {
                        const int s = __shfl(c, j, 16);
                        const float4 hv = *(const float4*)(bin + (size_t)s * 64 + q * 4);
                        const float wx = __shfl(w4.x, j, 16);
                        const float wy = __shfl(w4.y, j, 16);
                        const float wz = __shfl(w4.z, j, 16);
                        const float ww = __shfl(w4.w, j, 16);
                        acc[0][0] += wx * hv.x; acc[0][1] += wx * hv.y;
                        acc[0][2] += wx * hv.z; acc[0][3] += wx * hv.w;
                        acc[1][0] += wy * hv.x; acc[1][1] += wy * hv.y;
                        acc[1][2] += wy * hv.z; acc[1][3] += wy * hv.w;
                        acc[2][0] += wz * hv.x; acc[2][1] += wz * hv.y;
                        acc[2][2] += wz * hv.z; acc[2][3] += wz * hv.w;
                        acc[3][0] += ww * hv.x; acc[3][1] += ww * hv.y;
                        acc[3][2] += ww * hv.z; acc[3][3] += ww * hv.w;
                    }
                }
#pragma unroll
                for (int off = 1; off < 16; off <<= 1) {
                    den4.x += __shfl_xor(den4.x, off, 16);
                    den4.y += __shfl_xor(den4.y, off, 16);
                    den4.z += __shfl_xor(den4.z, off, 16);
                    den4.w += __shfl_xor(den4.w, off, 16);
                }
                const float i0 = 1.f / (den4.x + 1e-16f);
                const float i1 = 1.f / (den4.y + 1e-16f);
                const float i2 = 1.f / (den4.z + 1e-16f);
                const float i3 = 1.f / (den4.w + 1e-16f);
                float* gr = g + (size_t)n * 256 + q * 4;
                *(float4*)(gr +   0) = make_float4(acc[0][0]*i0, acc[0][1]*i0, acc[0][2]*i0, acc[0][3]*i0);
                *(float4*)(gr +  64) = make_float4(acc[1][0]*i1, acc[1][1]*i1, acc[1][2]*i1, acc[1][3]*i1);
                *(float4*)(gr + 128) = make_float4(acc[2][0]*i2, acc[2][1]*i2, acc[2][2]*i2, acc[2][3]*i2);
                *(float4*)(gr + 192) = make_float4(acc[3][0]*i3, acc[3][1]*i3, acc[3][2]*i3, acc[3][3]*i3);
            }
        }
        gbar(bar, 5 + l * 2);

        // ---- post: out = 0.25*(g@Wperm)+bias+residual; dots or fused MLP ----
        {
            float* gS = S;           // 64*66 = 4224
            float* Wp = S + 4224;    // 4096
            float* vN = S + 8320;    // 512
            const int cg = t & 7;
            const int ng = t >> 3;
            const int c0 = cg * 8;
            const int ntile = (N + 63) >> 6;
            for (int tile = b; tile < ntile; tile += GRID) {
                const int n0 = tile * 64;
                if (has_next && t < 128)
                    *(float4*)(vN + t * 4) = *(const float4*)(vnext + t * 4);
                float acc[2][8];
#pragma unroll
                for (int i = 0; i < 2; ++i)
#pragma unroll
                    for (int qq = 0; qq < 8; ++qq) acc[i][qq] = 0.f;
                for (int slab = 0; slab < 4; ++slab) {
                    __syncthreads();
                    // stage gS: 64 nodes x 64 k (stride 66); 4 float4/thread
#pragma unroll
                    for (int j = 0; j < 4; ++j) {
                        const int idx = j * 256 + t;
                        const int nl = idx >> 4;
                        const int c4 = idx & 15;
                        float4 v = make_float4(0.f, 0.f, 0.f, 0.f);
                        if (n0 + nl < N)
                            v = *(const float4*)(g + (size_t)(n0 + nl) * 256 + slab * 64 + c4 * 4);
                        *(float4*)(gS + nl * 66 + c4 * 4) = v;
                    }
                    // stage Wp[kl][c] = W[kk, h*64+c], kap = slab*64+kl
#pragma unroll
                    for (int j = 0; j < 4; ++j) {
                        const int f4 = j * 256 + t;
                        const int kl = f4 >> 4;
                        const int kap = slab * 64 + kl;
                        const int h = kap >> 6, kk = kap & 63;
                        const int c = (f4 & 15) * 4;
                        *(float4*)(Wp + kl * 64 + c) = *(const float4*)(W + kk * 256 + h * 64 + c);
                    }
                    __syncthreads();
#pragma unroll 4
                    for (int kl = 0; kl < 64; ++kl) {
                        const float a0 = gS[(ng * 2 + 0) * 66 + kl];
                        const float a1 = gS[(ng * 2 + 1) * 66 + kl];
                        const float4 b0 = *(const float4*)(Wp + kl * 64 + c0);
                        const float4 b1 = *(const float4*)(Wp + kl * 64 + c0 + 4);
                        acc[0][0] += a0 * b0.x; acc[0][1] += a0 * b0.y;
                        acc[0][2] += a0 * b0.z; acc[0][3] += a0 * b0.w;
                        acc[0][4] += a0 * b1.x; acc[0][5] += a0 * b1.y;
                        acc[0][6] += a0 * b1.z; acc[0][7] += a0 * b1.w;
                        acc[1][0] += a1 * b0.x; acc[1][1] += a1 * b0.y;
                        acc[1][2] += a1 * b0.z; acc[1][3] += a1 * b0.w;
                        acc[1][4] += a1 * b1.x; acc[1][5] += a1 * b1.y;
                        acc[1][6] += a1 * b1.z; acc[1][7] += a1 * b1.w;
                    }
                }
                const float4 bb0 = *(const float4*)(bias + c0);
                const float4 bb1 = *(const float4*)(bias + c0 + 4);
                float o[2][8];
#pragma unroll
                for (int i = 0; i < 2; ++i) {
                    const int n = n0 + ng * 2 + i;
                    if (n < N) {
                        const float4 x0 = *(const float4*)(bin + (size_t)n * 64 + c0);
                        const float4 x1 = *(const float4*)(bin + (size_t)n * 64 + c0 + 4);
                        o[i][0] = 0.25f * acc[i][0] + bb0.x + x0.x;
                        o[i][1] = 0.25f * acc[i][1] + bb0.y + x0.y;
                        o[i][2] = 0.25f * acc[i][2] + bb0.z + x0.z;
                        o[i][3] = 0.25f * acc[i][3] + bb0.w + x0.w;
                        o[i][4] = 0.25f * acc[i][4] + bb1.x + x1.x;
                        o[i][5] = 0.25f * acc[i][5] + bb1.y + x1.y;
                        o[i][6] = 0.25f * acc[i][6] + bb1.z + x1.z;
                        o[i][7] = 0.25f * acc[i][7] + bb1.w + x1.w;
                        if (has_next) {
                            *(float4*)(bout + (size_t)n * 64 + c0) =
                                make_float4(o[i][0], o[i][1], o[i][2], o[i][3]);
                            *(float4*)(bout + (size_t)n * 64 + c0 + 4) =
                                make_float4(o[i][4], o[i][5], o[i][6], o[i][7]);
                        }
                    } else {
#pragma unroll
                        for (int qq = 0; qq < 8; ++qq) o[i][qq] = 0.f;
                    }
                }

                if (has_next) {
                    float pj[2][8];
#pragma unroll
                    for (int i = 0; i < 2; ++i)
#pragma unroll
                        for (int jj = 0; jj < 8; ++jj) pj[i][jj] = 0.f;
#pragma unroll
                    for (int cidx = 0; cidx < 8; ++cidx) {
#pragma unroll
                        for (int jj = 0; jj < 8; ++jj) {
                            const float vv = vN[(c0 + cidx) * 8 + jj];
                            pj[0][jj] += o[0][cidx] * vv;
                            pj[1][jj] += o[1][cidx] * vv;
                        }
                    }
#pragma unroll
                    for (int off = 1; off < 8; off <<= 1) {
#pragma unroll
                        for (int i = 0; i < 2; ++i)
#pragma unroll
                            for (int jj = 0; jj < 8; ++jj)
                                pj[i][jj] += __shfl_xor(pj[i][jj], off);
                    }
                    if (cg == 0) {
#pragma unroll
                        for (int i = 0; i < 2; ++i) {
                            const int n = n0 + ng * 2 + i;
                            if (n < N) {
#pragma unroll
                                for (int h = 0; h < 4; ++h) {
                                    asrc[n * 4 + h] = pj[i][h];
                                    adst[n * 4 + h] = pj[i][4 + h];
                                }
                            }
                        }
                    }
                } else {
                    // ---- fused output MLP: h3 -> 64 -> 32 -> 8 ----
                    __syncthreads();  // k-loop LDS reads done
#pragma unroll
                    for (int i = 0; i < 2; ++i) {
                        const int nl = ng * 2 + i;
                        *(float4*)(gS + nl * 66 + c0) =
                            make_float4(o[i][0], o[i][1], o[i][2], o[i][3]);
                        *(float4*)(gS + nl * 66 + c0 + 4) =
                            make_float4(o[i][4], o[i][5], o[i][6], o[i][7]);
                    }
#pragma unroll
                    for (int j = 0; j < 4; ++j)
                        *(float4*)(Wp + (j * 256 + t) * 4) =
                            *(const float4*)(Wm1 + (j * 256 + t) * 4);
                    if (t < 64) vN[t] = bm1[t];
                    else if (t < 96) vN[t] = bm2[t - 64];
                    else if (t < 104) vN[t] = bm3[t - 96];
                    vN[104 + t] = Wm3[t];
                    __syncthreads();
                    // o1 = elu(h3 @ W1 + b1)
                    float a1[2][8];
#pragma unroll
                    for (int i = 0; i < 2; ++i)
#pragma unroll
                        for (int qq = 0; qq < 8; ++qq) a1[i][qq] = vN[c0 + qq];
#pragma unroll 4
                    for (int k = 0; k < 64; ++k) {
                        const float h0v = gS[(ng * 2 + 0) * 66 + k];
                        const float h1v = gS[(ng * 2 + 1) * 66 + k];
                        const float4 w0 = *(const float4*)(Wp + k * 64 + c0);
                        const float4 w1 = *(const float4*)(Wp + k * 64 + c0 + 4);
                        a1[0][0] += h0v * w0.x; a1[0][1] += h0v * w0.y;
                        a1[0][2] += h0v * w0.z; a1[0][3] += h0v * w0.w;
                        a1[0][4] += h0v * w1.x; a1[0][5] += h0v * w1.y;
                        a1[0][6] += h0v * w1.z; a1[0][7] += h0v * w1.w;
                        a1[1][0] += h1v * w0.x; a1[1][1] += h1v * w0.y;
                        a1[1][2] += h1v * w0.z; a1[1][3] += h1v * w0.w;
                        a1[1][4] += h1v * w1.x; a1[1][5] += h1v * w1.y;
                        a1[1][6] += h1v * w1.z; a1[1][7] += h1v * w1.w;
                    }
                    __syncthreads();  // h3/W1 reads done -> overwrite
#pragma unroll
                    for (int i = 0; i < 2; ++i) {
                        const int nl = ng * 2 + i;
                        *(float4*)(gS + nl * 66 + c0) =
                            make_float4(elu_f(a1[i][0]), elu_f(a1[i][1]),
                                        elu_f(a1[i][2]), elu_f(a1[i][3]));
                        *(float4*)(gS + nl * 66 + c0 + 4) =
                            make_float4(elu_f(a1[i][4]), elu_f(a1[i][5]),
                                        elu_f(a1[i][6]), elu_f(a1[i][7]));
                    }
#pragma unroll
                    for (int j = 0; j < 2; ++j)
                        *(float4*)(Wp + (j * 256 + t) * 4) =
                            *(const float4*)(Wm2 + (j * 256 + t) * 4);
                    __syncthreads();
                    // o2 = elu(o1 @ W2 + b2)
                    {
                        const int cg4 = t & 3;
                        const int nn = t >> 2;
                        const int cc0 = cg4 * 8;
                        float a2[8];
#pragma unroll
                        for (int qq = 0; qq < 8; ++qq) a2[qq] = vN[64 + cc0 + qq];
#pragma unroll 4
                        for (int j = 0; j < 64; ++j) {
                            const float ov = gS[nn * 66 + j];
                            const float4 w0 = *(const float4*)(Wp + j * 32 + cc0);
                            const float4 w1 = *(const float4*)(Wp + j * 32 + cc0 + 4);
                            a2[0] += ov * w0.x; a2[1] += ov * w0.y;
                            a2[2] += ov * w0.z; a2[3] += ov * w0.w;
                            a2[4] += ov * w1.x; a2[5] += ov * w1.y;
                            a2[6] += ov * w1.z; a2[7] += ov * w1.w;
                        }
                        __syncthreads();  // o1 reads done
                        *(float4*)(gS + nn * 66 + cc0) =
                            make_float4(elu_f(a2[0]), elu_f(a2[1]), elu_f(a2[2]), elu_f(a2[3]));
                        *(float4*)(gS + nn * 66 + cc0 + 4) =
                            make_float4(elu_f(a2[4]), elu_f(a2[5]), elu_f(a2[6]), elu_f(a2[7]));
                    }
                    __syncthreads();
                    // out = o2 @ W3 + b3
                    {
                        const int c3 = t & 7;
                        const int nq2 = t >> 3;
#pragma unroll
                        for (int i = 0; i < 2; ++i) {
                            const int nl = nq2 * 2 + i;
                            const int n = n0 + nl;
                            if (n >= N) continue;
                            float a3 = vN[96 + c3];
#pragma unroll 4
                            for (int j = 0; j < 32; ++j)
                                a3 += gS[nl * 66 + j] * vN[104 + j * 8 + c3];
                            outp[(size_t)n * 8 + c3] = a3;
                        }
                    }
                }
            }
        }
        if (l < 2) gbar(bar, 6 + l * 2);
    }
}

// ---------------------------------------------------------------------------
extern "C" void kernel_launch(void* const* d_in, const int* in_sizes, int n_in,
                              void* d_out, int out_size, void* d_ws, size_t ws_size,
                              hipStream_t stream) {
    const float* x     = (const float*)d_in[0];
    const int*   ei    = (const int*)d_in[1];
    const float* Wenc1 = (const float*)d_in[2];
    const float* benc1 = (const float*)d_in[3];
    const float* Wenc2 = (const float*)d_in[4];
    const float* benc2 = (const float*)d_in[5];

    const int N = in_sizes[0] / 8;
    const int E = in_sizes[1] / 2;

    float* buf0  = (float*)d_ws;                  // N*64
    float* buf1  = buf0 + (size_t)N * 64;         // N*64
    float* g     = buf1 + (size_t)N * 64;         // N*256
    float* asrc  = g + (size_t)N * 256;           // N*4
    float* adst  = asrc + (size_t)N * 4;          // N*4
    float* vfold = adst + (size_t)N * 4;          // 3*512
    int* rowptr = (int*)(vfold + 3 * 512);        // N+1 (+pad)
    int* cursor = rowptr + (N + 2);               // N
    int* cnt    = cursor + N;                     // N
    int* ready  = cnt + N;                        // 128
    int* flag   = ready + 128;                    // 1 (+pad)
    int* bar    = flag + 2;                       // 16
    int* col    = bar + 16;                       // Etot

    init_kernel<<<1, 64, 0, stream>>>(bar);
    mega_kernel<<<GRID, NTHR, 0, stream>>>(
        x, ei, Wenc1, benc1, Wenc2, benc2,
        (const float*)d_in[6],  (const float*)d_in[7],  (const float*)d_in[8],  (const float*)d_in[9],
        (const float*)d_in[10], (const float*)d_in[11], (const float*)d_in[12], (const float*)d_in[13],
        (const float*)d_in[14], (const float*)d_in[15], (const float*)d_in[16], (const float*)d_in[17],
        (const float*)d_in[18], (const float*)d_in[19],
        (const float*)d_in[20], (const float*)d_in[21],
        (const float*)d_in[22], (const float*)d_in[23],
        buf0, buf1, g, asrc, adst, vfold,
        rowptr, cursor, cnt, ready, flag, col, bar,
        (float*)d_out, N, E);
}

// Round 10
// 359.927 us; speedup vs baseline: 5.0735x; 5.0735x over previous
//
#include <hip/hip_runtime.h>
#include <cstdint>
#include <cstddef>

#define NEG_SLOPE 0.2f

__device__ __forceinline__ float elu_f(float x) {
    return x > 0.f ? x : expm1f(x);
}

// ---------------------------------------------------------------------------
// countenc: disjoint block ranges, independent work (no cross-block deps).
//   blocks [0, nblkE):          degree count (self-detects int64 layout)
//   blocks [nblkE, nblkE+nEnc): encoder 64-node LDS GEMM + self-folded
//                               layer-0 attention dots
//   blocks [nblkE+nEnc, +4):    fold vfold for layers 1,2
// ---------------------------------------------------------------------------
#define H1STR 68
__global__ __launch_bounds__(256) void countenc_kernel(
    const int* __restrict__ ei, const float* __restrict__ x,
    const float* __restrict__ Wenc1, const float* __restrict__ benc1,
    const float* __restrict__ Wenc2, const float* __restrict__ benc2,
    const float* __restrict__ Wg0, const float* __restrict__ as0,
    const float* __restrict__ ad0,
    const float* __restrict__ Wg1, const float* __restrict__ as1,
    const float* __restrict__ ad1,
    const float* __restrict__ Wg2, const float* __restrict__ as2,
    const float* __restrict__ ad2,
    int* __restrict__ cnt, float* __restrict__ vfold,
    float* __restrict__ h0, float* __restrict__ asrc, float* __restrict__ adst,
    int N, int E, int nblkE, int nEnc) {
    const int b = blockIdx.x, t = threadIdx.x;
    const int Etot = E + N;

    __shared__ float W1s[256];
    __shared__ float b1s[32];
    __shared__ float b2s[64];
    __shared__ float vsd[512];
    __shared__ float xS[512];
    __shared__ float W2s[2048];
    __shared__ float h1T[32 * H1STR];
    __shared__ int sflag;

    // ---- count path ----
    if (b < nblkE) {
        if (t == 0) {
            int acc = 0;
#pragma unroll
            for (int k = 0; k < 8; ++k) acc |= ei[2 * k + 1];
            sflag = (acc == 0) ? 1 : 0;
        }
        __syncthreads();
        const int e = b * 256 + t;
        if (e < Etot) {
            int d;
            if (e < E) d = sflag ? ei[2 * (size_t)(E + e)] : ei[E + e];
            else       d = e - E;  // self loop
            atomicAdd(&cnt[d], 1);
        }
        return;
    }
    // ---- fold path (layers 1,2) ----
    if (b >= nblkE + nEnc) {
        const int e = (b - nblkE - nEnc) * 256 + t;
        if (e < 1024) {
            const int l = 1 + (e >> 9), rem = e & 511;
            const int k = rem >> 3, j = rem & 7, h = j & 3;
            const float* W   = (l == 1) ? Wg1 : Wg2;
            const float* asl = (l == 1) ? as1 : as2;
            const float* adl = (l == 1) ? ad1 : ad2;
            const float* av = (j < 4) ? asl : adl;
            const float* wr = W + k * 256 + h * 64;
            const float* ar = av + h * 64;
            float s = 0.f;
#pragma unroll 8
            for (int cc = 0; cc < 64; ++cc) s += wr[cc] * ar[cc];
            vfold[l * 512 + k * 8 + j] = s;
        }
        return;
    }

    // ---- encoder path ----
    const int n0 = (b - nblkE) * 64;
    const int rem = N - n0;
    // stage weights + x tile
    *(float4*)(W2s + t * 4) = *(const float4*)(Wenc2 + t * 4);
    *(float4*)(W2s + 1024 + t * 4) = *(const float4*)(Wenc2 + 1024 + t * 4);
    if (t < 64)  *(float4*)(W1s + t * 4) = *(const float4*)(Wenc1 + t * 4);
    if (t < 8)   *(float4*)(b1s + t * 4) = *(const float4*)(benc1 + t * 4);
    if (t < 16)  *(float4*)(b2s + t * 4) = *(const float4*)(benc2 + t * 4);
    if (t < 128) {
        const int fidx = t * 4;
        float4 v = make_float4(0.f, 0.f, 0.f, 0.f);
        if (fidx < rem * 8) v = *(const float4*)(x + (size_t)n0 * 8 + fidx);
        *(float4*)(xS + fidx) = v;
    }
    // self-fold layer-0 attention vectors into vsd (same dot order as before)
#pragma unroll
    for (int u = 0; u < 2; ++u) {
        const int e2 = t * 2 + u;
        const int k = e2 >> 3, j = e2 & 7, h = j & 3;
        const float* av = (j < 4) ? as0 : ad0;
        const float* wr = Wg0 + k * 256 + h * 64;
        const float* ar = av + h * 64;
        float s = 0.f;
#pragma unroll 8
        for (int cc = 0; cc < 64; ++cc) s += wr[cc] * ar[cc];
        vsd[k * 8 + j] = s;
    }
    __syncthreads();
    {   // phase A: h1 = elu(x@W1+b1) -> h1T
        const int nl = t >> 2;
        const int j0 = (t & 3) * 8;
        const float4 xa = *(const float4*)(xS + nl * 8);
        const float4 xb = *(const float4*)(xS + nl * 8 + 4);
        const float xk[8] = {xa.x, xa.y, xa.z, xa.w, xb.x, xb.y, xb.z, xb.w};
        float a[8];
#pragma unroll
        for (int u = 0; u < 8; ++u) a[u] = b1s[j0 + u];
#pragma unroll
        for (int k = 0; k < 8; ++k) {
            const float4 w0 = *(const float4*)(W1s + k * 32 + j0);
            const float4 w1 = *(const float4*)(W1s + k * 32 + j0 + 4);
            a[0] += xk[k] * w0.x; a[1] += xk[k] * w0.y;
            a[2] += xk[k] * w0.z; a[3] += xk[k] * w0.w;
            a[4] += xk[k] * w1.x; a[5] += xk[k] * w1.y;
            a[6] += xk[k] * w1.z; a[7] += xk[k] * w1.w;
        }
#pragma unroll
        for (int u = 0; u < 8; ++u) h1T[(j0 + u) * H1STR + nl] = elu_f(a[u]);
    }
    __syncthreads();
    {   // phase B: h0 = elu(h1@W2+b2) + fused layer-0 dots
        const int cg = t & 15;
        const int nq = t >> 4;
        const int c0 = cg * 4;
        float acc[4][4];
#pragma unroll
        for (int i = 0; i < 4; ++i)
#pragma unroll
            for (int c = 0; c < 4; ++c) acc[i][c] = b2s[c0 + c];
#pragma unroll 8
        for (int k = 0; k < 32; ++k) {
            const float4 hv = *(const float4*)(h1T + k * H1STR + nq * 4);
            const float4 wv = *(const float4*)(W2s + k * 64 + c0);
            const float hvv[4] = {hv.x, hv.y, hv.z, hv.w};
#pragma unroll
            for (int i = 0; i < 4; ++i) {
                acc[i][0] += hvv[i] * wv.x; acc[i][1] += hvv[i] * wv.y;
                acc[i][2] += hvv[i] * wv.z; acc[i][3] += hvv[i] * wv.w;
            }
        }
        float o[4][4];
#pragma unroll
        for (int i = 0; i < 4; ++i)
#pragma unroll
            for (int c = 0; c < 4; ++c) o[i][c] = elu_f(acc[i][c]);
#pragma unroll
        for (int i = 0; i < 4; ++i) {
            const int n = n0 + nq * 4 + i;
            if (n < N)
                *(float4*)(h0 + (size_t)n * 64 + c0) =
                    make_float4(o[i][0], o[i][1], o[i][2], o[i][3]);
        }
        float ad[4][8];
#pragma unroll
        for (int i = 0; i < 4; ++i)
#pragma unroll
            for (int jj = 0; jj < 8; ++jj) ad[i][jj] = 0.f;
#pragma unroll
        for (int c = 0; c < 4; ++c) {
            const float4 v0 = *(const float4*)(vsd + (c0 + c) * 8);
            const float4 v1 = *(const float4*)(vsd + (c0 + c) * 8 + 4);
#pragma unroll
            for (int i = 0; i < 4; ++i) {
                ad[i][0] += o[i][c] * v0.x; ad[i][1] += o[i][c] * v0.y;
                ad[i][2] += o[i][c] * v0.z; ad[i][3] += o[i][c] * v0.w;
                ad[i][4] += o[i][c] * v1.x; ad[i][5] += o[i][c] * v1.y;
                ad[i][6] += o[i][c] * v1.z; ad[i][7] += o[i][c] * v1.w;
            }
        }
#pragma unroll
        for (int off = 1; off < 16; off <<= 1) {
#pragma unroll
            for (int i = 0; i < 4; ++i)
#pragma unroll
                for (int jj = 0; jj < 8; ++jj)
                    ad[i][jj] += __shfl_xor(ad[i][jj], off);
        }
        if (cg == 0) {
#pragma unroll
            for (int i = 0; i < 4; ++i) {
                const int n = n0 + nq * 4 + i;
                if (n < N) {
#pragma unroll
                    for (int h = 0; h < 4; ++h) {
                        asrc[n * 4 + h] = ad[i][h];
                        adst[n * 4 + h] = ad[i][4 + h];
                    }
                }
            }
        }
    }
}

// ---------------------------------------------------------------------------
// scanfill: blocks 0..nscan-1 run the lookback scan then arrive at sdone;
// fill blocks wait on sdone with LOAD-ONLY polling (single-writer word, no
// RMW ping-pong — the R9 failure mode). Grid 1408 <= 6 blocks/CU * 256 CU
// (launch_bounds(256,6), ~1.7KB LDS) => all blocks co-resident => no
// dispatch-order deadlock.
// ---------------------------------------------------------------------------
__global__ __launch_bounds__(256, 6) void scanfill_kernel(
    const int* __restrict__ ei, const int* __restrict__ cnt,
    int* __restrict__ ready, int* __restrict__ sdone,
    int* __restrict__ rowptr, int* __restrict__ cursor, int* __restrict__ col,
    int N, int E) {
    __shared__ int sd[256];
    __shared__ int sred[128];
    __shared__ int sprf;
    __shared__ int sflag;
    const int b = blockIdx.x, t = threadIdx.x;
    const int Etot = E + N;
    const int nscan = (N + 255) >> 8;

    if (b < nscan) {
        const int gi = b * 256 + t;
        const int v = (gi < N) ? cnt[gi] : 0;
        sd[t] = v;
        __syncthreads();
        for (int off = 1; off < 256; off <<= 1) {
            int add = (t >= off) ? sd[t - off] : 0;
            __syncthreads();
            sd[t] += add;
            __syncthreads();
        }
        if (t == 255) atomicExch(&ready[b], sd[255] + 1);
        if (t < 128) {
            int pv = 0;
            if (t < b) {
                do { pv = atomicAdd(&ready[t], 0); __builtin_amdgcn_s_sleep(1); } while (pv == 0);
                pv -= 1;
            }
            sred[t] = pv;
        }
        __syncthreads();
        if (t == 0) {
            int s = 0;
#pragma unroll 8
            for (int i = 0; i < 128; ++i) s += sred[i];
            sprf = s;
        }
        __syncthreads();
        const int pre = sprf;
        if (gi < N) {
            const int e = pre + sd[t];
            rowptr[gi + 1] = e;
            cursor[gi] = e - v;
            if (gi == 0) rowptr[0] = 0;
        }
        __threadfence();
        __syncthreads();
        if (t == 0) atomicAdd(sdone, 1);
        return;
    }

    // ---- fill path: wait for scan completion (load-only poll) ----
    if (t == 0) {
        int acc = 0;
#pragma unroll
        for (int k = 0; k < 8; ++k) acc |= ei[2 * k + 1];
        sflag = (acc == 0) ? 1 : 0;
        while (__hip_atomic_load(sdone, __ATOMIC_ACQUIRE, __HIP_MEMORY_SCOPE_AGENT) < nscan)
            __builtin_amdgcn_s_sleep(4);
    }
    __syncthreads();
    const int e = (b - nscan) * 256 + t;
    if (e < Etot) {
        int s, d;
        if (e < E) {
            if (sflag) { s = ei[2 * (size_t)e]; d = ei[2 * (size_t)(E + e)]; }
            else       { s = ei[e];             d = ei[E + e]; }
        } else {
            s = d = e - E;
        }
        int pos = atomicAdd(&cursor[d], 1);
        col[pos] = s;
    }
}

// ---------------------------------------------------------------------------
// GAT aggregation: one 16-lane group per dst node (4 nodes/wave, 16/block).
// (unchanged from R8)
// ---------------------------------------------------------------------------
__global__ __launch_bounds__(256) void gat_agg_kernel(
    const float* __restrict__ bin, const float* __restrict__ asrc,
    const float* __restrict__ adst, const int* __restrict__ rowptr,
    const int* __restrict__ col, float* __restrict__ g, int n_nodes) {
    const int grp = threadIdx.x >> 4;
    const int q = threadIdx.x & 15;
    const int n = blockIdx.x * 16 + grp;
    if (n >= n_nodes) return;
    const float4 ad4 = *(const float4*)(adst + (size_t)n * 4);
    const int start = rowptr[n], end = rowptr[n + 1];

    float acc[4][4];
#pragma unroll
    for (int h = 0; h < 4; ++h)
#pragma unroll
        for (int z = 0; z < 4; ++z) acc[h][z] = 0.f;
    float4 den4 = make_float4(0.f, 0.f, 0.f, 0.f);

    for (int base = start; base < end; base += 16) {
        const int cnt2 = min(16, end - base);
        int c = 0;
        float4 w4 = make_float4(0.f, 0.f, 0.f, 0.f);
        if (base + q < end) {
            c = col[base + q];
            const float4 av = *(const float4*)(asrc + (size_t)c * 4);
            float l0 = av.x + ad4.x; l0 = l0 > 0.f ? l0 : NEG_SLOPE * l0;
            float l1 = av.y + ad4.y; l1 = l1 > 0.f ? l1 : NEG_SLOPE * l1;
            float l2 = av.z + ad4.z; l2 = l2 > 0.f ? l2 : NEG_SLOPE * l2;
            float l3 = av.w + ad4.w; l3 = l3 > 0.f ? l3 : NEG_SLOPE * l3;
            w4.x = __expf(fminf(l0, 60.f));
            w4.y = __expf(fminf(l1, 60.f));
            w4.z = __expf(fminf(l2, 60.f));
            w4.w = __expf(fminf(l3, 60.f));
            den4.x += w4.x; den4.y += w4.y; den4.z += w4.z; den4.w += w4.w;
        }
        int j = 0;
        for (; j + 4 <= cnt2; j += 4) {
#pragma unroll
            for (int u = 0; u < 4; ++u) {
                const int s = __shfl(c, j + u, 16);
                const float4 hv = *(const float4*)(bin + (size_t)s * 64 + q * 4);
                const float wx = __shfl(w4.x, j + u, 16);
                const float wy = __shfl(w4.y, j + u, 16);
                const float wz = __shfl(w4.z, j + u, 16);
                const float ww = __shfl(w4.w, j + u, 16);
                acc[0][0] += wx * hv.x; acc[0][1] += wx * hv.y;
                acc[0][2] += wx * hv.z; acc[0][3] += wx * hv.w;
                acc[1][0] += wy * hv.x; acc[1][1] += wy * hv.y;
                acc[1][2] += wy * hv.z; acc[1][3] += wy * hv.w;
                acc[2][0] += wz * hv.x; acc[2][1] += wz * hv.y;
                acc[2][2] += wz * hv.z; acc[2][3] += wz * hv.w;
                acc[3][0] += ww * hv.x; acc[3][1] += ww * hv.y;
                acc[3][2] += ww * hv.z; acc[3][3] += ww * hv.w;
            }
        }
        for (; j < cnt2; ++j) {
            const int s = __shfl(c, j, 16);
            const float4 hv = *(const float4*)(bin + (size_t)s * 64 + q * 4);
            const float wx = __shfl(w4.x, j, 16);
            const float wy = __shfl(w4.y, j, 16);
            const float wz = __shfl(w4.z, j, 16);
            const float ww = __shfl(w4.w, j, 16);
            acc[0][0] += wx * hv.x; acc[0][1] += wx * hv.y;
            acc[0][2] += wx * hv.z; acc[0][3] += wx * hv.w;
            acc[1][0] += wy * hv.x; acc[1][1] += wy * hv.y;
            acc[1][2] += wy * hv.z; acc[1][3] += wy * hv.w;
            acc[2][0] += wz * hv.x; acc[2][1] += wz * hv.y;
            acc[2][2] += wz * hv.z; acc[2][3] += wz * hv.w;
            acc[3][0] += ww * hv.x; acc[3][1] += ww * hv.y;
            acc[3][2] += ww * hv.z; acc[3][3] += ww * hv.w;
        }
    }
#pragma unroll
    for (int off = 1; off < 16; off <<= 1) {
        den4.x += __shfl_xor(den4.x, off, 16);
        den4.y += __shfl_xor(den4.y, off, 16);
        den4.z += __shfl_xor(den4.z, off, 16);
        den4.w += __shfl_xor(den4.w, off, 16);
    }
    const float i0 = 1.f / (den4.x + 1e-16f);
    const float i1 = 1.f / (den4.y + 1e-16f);
    const float i2 = 1.f / (den4.z + 1e-16f);
    const float i3 = 1.f / (den4.w + 1e-16f);
    float* gr = g + (size_t)n * 256 + q * 4;
    *(float4*)(gr +   0) = make_float4(acc[0][0]*i0, acc[0][1]*i0, acc[0][2]*i0, acc[0][3]*i0);
    *(float4*)(gr +  64) = make_float4(acc[1][0]*i1, acc[1][1]*i1, acc[1][2]*i1, acc[1][3]*i1);
    *(float4*)(gr + 128) = make_float4(acc[2][0]*i2, acc[2][1]*i2, acc[2][2]*i2, acc[2][3]*i2);
    *(float4*)(gr + 192) = make_float4(acc[3][0]*i3, acc[3][1]*i3, acc[3][2]*i3, acc[3][3]*i3);
}

// ---------------------------------------------------------------------------
// GAT post-projection (unchanged from R8). has_next=1: fused next-layer dots.
// has_next=0: fused output MLP 64->64->32->8, writes d_out directly.
// ---------------------------------------------------------------------------
#define GSTR 132
__global__ __launch_bounds__(256) void gat_post_kernel(
    const float* __restrict__ g, const float* __restrict__ W,
    const float* __restrict__ bias, const float* __restrict__ xin,
    const float* __restrict__ vfold_next, int has_next,
    float* __restrict__ out, float* __restrict__ asrc, float* __restrict__ adst,
    const float* __restrict__ Wm1, const float* __restrict__ bm1,
    const float* __restrict__ Wm2, const float* __restrict__ bm2,
    const float* __restrict__ Wm3, const float* __restrict__ bm3,
    float* __restrict__ mlp_out, int n_nodes) {
    __shared__ float gS[64 * GSTR];
    __shared__ float Wp[128 * 64];
    __shared__ float vN[512];
    const int t = threadIdx.x;
    const int n0 = blockIdx.x * 64;
    const int cg = t & 7;
    const int ng = t >> 3;

    if (has_next && t < 128) *(float4*)(vN + t * 4) = *(const float4*)(vfold_next + t * 4);

    float acc[2][8];
#pragma unroll
    for (int i = 0; i < 2; ++i)
#pragma unroll
        for (int qq = 0; qq < 8; ++qq) acc[i][qq] = 0.f;

    for (int slab = 0; slab < 2; ++slab) {
        __syncthreads();
#pragma unroll
        for (int j = 0; j < 8; ++j) {
            const int idx = j * 256 + t;
            const int nl = idx >> 5;
            const int c4 = idx & 31;
            float4 v = make_float4(0.f, 0.f, 0.f, 0.f);
            if (n0 + nl < n_nodes)
                v = *(const float4*)(g + (size_t)(n0 + nl) * 256 + slab * 128 + c4 * 4);
            *(float4*)(gS + nl * GSTR + c4 * 4) = v;
        }
#pragma unroll
        for (int j = 0; j < 8; ++j) {
            const int f4 = j * 256 + t;
            const int kl = f4 >> 4;
            const int kap = slab * 128 + kl;
            const int h = kap >> 6, kk = kap & 63;
            const int c = (f4 & 15) * 4;
            *(float4*)(Wp + kl * 64 + c) = *(const float4*)(W + kk * 256 + h * 64 + c);
        }
        __syncthreads();
#pragma unroll 4
        for (int kl = 0; kl < 128; ++kl) {
            const float a0 = gS[(ng * 2 + 0) * GSTR + kl];
            const float a1 = gS[(ng * 2 + 1) * GSTR + kl];
            const float4 b0 = *(const float4*)(Wp + kl * 64 + cg * 8);
            const float4 b1 = *(const float4*)(Wp + kl * 64 + cg * 8 + 4);
            acc[0][0] += a0 * b0.x; acc[0][1] += a0 * b0.y;
            acc[0][2] += a0 * b0.z; acc[0][3] += a0 * b0.w;
            acc[0][4] += a0 * b1.x; acc[0][5] += a0 * b1.y;
            acc[0][6] += a0 * b1.z; acc[0][7] += a0 * b1.w;
            acc[1][0] += a1 * b0.x; acc[1][1] += a1 * b0.y;
            acc[1][2] += a1 * b0.z; acc[1][3] += a1 * b0.w;
            acc[1][4] += a1 * b1.x; acc[1][5] += a1 * b1.y;
            acc[1][6] += a1 * b1.z; acc[1][7] += a1 * b1.w;
        }
    }

    const int c0 = cg * 8;
    const float4 bb0 = *(const float4*)(bias + c0);
    const float4 bb1 = *(const float4*)(bias + c0 + 4);
    float o[2][8];
#pragma unroll
    for (int i = 0; i < 2; ++i) {
        const int n = n0 + ng * 2 + i;
        if (n < n_nodes) {
            const float4 x0 = *(const float4*)(xin + (size_t)n * 64 + c0);
            const float4 x1 = *(const float4*)(xin + (size_t)n * 64 + c0 + 4);
            o[i][0] = 0.25f * acc[i][0] + bb0.x + x0.x;
            o[i][1] = 0.25f * acc[i][1] + bb0.y + x0.y;
            o[i][2] = 0.25f * acc[i][2] + bb0.z + x0.z;
            o[i][3] = 0.25f * acc[i][3] + bb0.w + x0.w;
            o[i][4] = 0.25f * acc[i][4] + bb1.x + x1.x;
            o[i][5] = 0.25f * acc[i][5] + bb1.y + x1.y;
            o[i][6] = 0.25f * acc[i][6] + bb1.z + x1.z;
            o[i][7] = 0.25f * acc[i][7] + bb1.w + x1.w;
            if (has_next) {
                *(float4*)(out + (size_t)n * 64 + c0) =
                    make_float4(o[i][0], o[i][1], o[i][2], o[i][3]);
                *(float4*)(out + (size_t)n * 64 + c0 + 4) =
                    make_float4(o[i][4], o[i][5], o[i][6], o[i][7]);
            }
        } else {
#pragma unroll
            for (int qq = 0; qq < 8; ++qq) o[i][qq] = 0.f;
        }
    }

    if (has_next) {
        float pj[2][8];
#pragma unroll
        for (int i = 0; i < 2; ++i)
#pragma unroll
            for (int jj = 0; jj < 8; ++jj) pj[i][jj] = 0.f;
#pragma unroll
        for (int cidx = 0; cidx < 8; ++cidx) {
#pragma unroll
            for (int jj = 0; jj < 8; ++jj) {
                const float vv = vN[(c0 + cidx) * 8 + jj];
                pj[0][jj] += o[0][cidx] * vv;
                pj[1][jj] += o[1][cidx] * vv;
            }
        }
#pragma unroll
        for (int off = 1; off < 8; off <<= 1) {
#pragma unroll
            for (int i = 0; i < 2; ++i)
#pragma unroll
                for (int jj = 0; jj < 8; ++jj)
                    pj[i][jj] += __shfl_xor(pj[i][jj], off);
        }
        if (cg == 0) {
#pragma unroll
            for (int i = 0; i < 2; ++i) {
                const int n = n0 + ng * 2 + i;
                if (n < n_nodes) {
#pragma unroll
                    for (int h = 0; h < 4; ++h) {
                        asrc[n * 4 + h] = pj[i][h];
                        adst[n * 4 + h] = pj[i][4 + h];
                    }
                }
            }
        }
        return;
    }

    // ---- fused output MLP (last layer) ----
    __syncthreads();
#pragma unroll
    for (int i = 0; i < 2; ++i) {
        const int nl = ng * 2 + i;
        *(float4*)(gS + nl * GSTR + c0)     = make_float4(o[i][0], o[i][1], o[i][2], o[i][3]);
        *(float4*)(gS + nl * GSTR + c0 + 4) = make_float4(o[i][4], o[i][5], o[i][6], o[i][7]);
    }
    {
#pragma unroll
        for (int j = 0; j < 4; ++j)
            *(float4*)(Wp + (j * 256 + t) * 4) = *(const float4*)(Wm1 + (j * 256 + t) * 4);
#pragma unroll
        for (int j = 0; j < 2; ++j)
            *(float4*)(Wp + 4096 + (j * 256 + t) * 4) = *(const float4*)(Wm2 + (j * 256 + t) * 4);
        if (t < 64) vN[t] = bm1[t];
        else if (t < 96) vN[t] = bm2[t - 64];
        else if (t < 104) vN[t] = bm3[t - 96];
        vN[104 + t] = Wm3[t];
    }
    __syncthreads();
    {
        float a1[2][8];
#pragma unroll
        for (int i = 0; i < 2; ++i)
#pragma unroll
            for (int qq = 0; qq < 8; ++qq) a1[i][qq] = vN[c0 + qq];
#pragma unroll 4
        for (int k = 0; k < 64; ++k) {
            const float h0 = gS[(ng * 2 + 0) * GSTR + k];
            const float h1v = gS[(ng * 2 + 1) * GSTR + k];
            const float4 w0 = *(const float4*)(Wp + k * 64 + c0);
            const float4 w1 = *(const float4*)(Wp + k * 64 + c0 + 4);
            a1[0][0] += h0 * w0.x; a1[0][1] += h0 * w0.y;
            a1[0][2] += h0 * w0.z; a1[0][3] += h0 * w0.w;
            a1[0][4] += h0 * w1.x; a1[0][5] += h0 * w1.y;
            a1[0][6] += h0 * w1.z; a1[0][7] += h0 * w1.w;
            a1[1][0] += h1v * w0.x; a1[1][1] += h1v * w0.y;
            a1[1][2] += h1v * w0.z; a1[1][3] += h1v * w0.w;
            a1[1][4] += h1v * w1.x; a1[1][5] += h1v * w1.y;
            a1[1][6] += h1v * w1.z; a1[1][7] += h1v * w1.w;
        }
#pragma unroll
        for (int i = 0; i < 2; ++i) {
            const int nl = ng * 2 + i;
            float4 v0 = make_float4(elu_f(a1[i][0]), elu_f(a1[i][1]), elu_f(a1[i][2]), elu_f(a1[i][3]));
            float4 v1 = make_float4(elu_f(a1[i][4]), elu_f(a1[i][5]), elu_f(a1[i][6]), elu_f(a1[i][7]));
            *(float4*)(gS + nl * GSTR + 64 + c0)     = v0;
            *(float4*)(gS + nl * GSTR + 64 + c0 + 4) = v1;
        }
    }
    __syncthreads();
    {
        const int cg4 = t & 3;
        const int nn = t >> 2;
        const int cc0 = cg4 * 8;
        float a2[8];
#pragma unroll
        for (int qq = 0; qq < 8; ++qq) a2[qq] = vN[64 + cc0 + qq];
#pragma unroll 4
        for (int j = 0; j < 64; ++j) {
            const float ov = gS[nn * GSTR + 64 + j];
            const float4 w0 = *(const float4*)(Wp + 4096 + j * 32 + cc0);
            const float4 w1 = *(const float4*)(Wp + 4096 + j * 32 + cc0 + 4);
            a2[0] += ov * w0.x; a2[1] += ov * w0.y;
            a2[2] += ov * w0.z; a2[3] += ov * w0.w;
            a2[4] += ov * w1.x; a2[5] += ov * w1.y;
            a2[6] += ov * w1.z; a2[7] += ov * w1.w;
        }
        __syncthreads();
        *(float4*)(gS + nn * GSTR + cc0)     = make_float4(elu_f(a2[0]), elu_f(a2[1]), elu_f(a2[2]), elu_f(a2[3]));
        *(float4*)(gS + nn * GSTR + cc0 + 4) = make_float4(elu_f(a2[4]), elu_f(a2[5]), elu_f(a2[6]), elu_f(a2[7]));
    }
    __syncthreads();
    {
        const int c3 = t & 7;
        const int nq = t >> 3;
#pragma unroll
        for (int i = 0; i < 2; ++i) {
            const int nl = nq * 2 + i;
            const int n = n0 + nl;
            if (n >= n_nodes) continue;
            float a3 = vN[96 + c3];
#pragma unroll 4
            for (int j = 0; j < 32; ++j)
                a3 += gS[nl * GSTR + j] * vN[104 + j * 8 + c3];
            mlp_out[(size_t)n * 8 + c3] = a3;
        }
    }
}

// ---------------------------------------------------------------------------
extern "C" void kernel_launch(void* const* d_in, const int* in_sizes, int n_in,
                              void* d_out, int out_size, void* d_ws, size_t ws_size,
                              hipStream_t stream) {
    const float* x     = (const float*)d_in[0];
    const int*   ei    = (const int*)d_in[1];
    const float* Wenc1 = (const float*)d_in[2];
    const float* benc1 = (const float*)d_in[3];
    const float* Wenc2 = (const float*)d_in[4];
    const float* benc2 = (const float*)d_in[5];
    const float* Wg[3]  = {(const float*)d_in[6],  (const float*)d_in[10], (const float*)d_in[14]};
    const float* as_[3] = {(const float*)d_in[7],  (const float*)d_in[11], (const float*)d_in[15]};
    const float* ad_[3] = {(const float*)d_in[8],  (const float*)d_in[12], (const float*)d_in[16]};
    const float* bg[3]  = {(const float*)d_in[9],  (const float*)d_in[13], (const float*)d_in[17]};
    const float* Wo1 = (const float*)d_in[18];
    const float* bo1 = (const float*)d_in[19];
    const float* Wo2 = (const float*)d_in[20];
    const float* bo2 = (const float*)d_in[21];
    const float* Wo3 = (const float*)d_in[22];
    const float* bo3 = (const float*)d_in[23];

    const int N = in_sizes[0] / 8;
    const int E = in_sizes[1] / 2;
    const int Etot = E + N;
    const int nblkE = (Etot + 255) / 256;
    const int nEnc  = (N + 63) / 64;
    const int nscan = (N + 255) / 256;

    float* buf0  = (float*)d_ws;                  // N*64
    float* buf1  = buf0 + (size_t)N * 64;         // N*64
    float* g     = buf1 + (size_t)N * 64;         // N*256
    float* asrc  = g + (size_t)N * 256;           // N*4
    float* adst  = asrc + (size_t)N * 4;          // N*4
    float* vfold = adst + (size_t)N * 4;          // 3*512
    int* rowptr = (int*)(vfold + 3 * 512);        // N+1 (+pad)
    int* cursor = rowptr + (N + 2);               // N
    int* cnt    = cursor + N;                     // N    <- memset region start
    int* ready  = cnt + N;                        // 128
    int* sdone  = ready + 128;                    // 1 (+pad to 8)
    int* col    = sdone + 8;                      // Etot

    // zero cnt + ready + sdone in one async memset (graph-capturable)
    hipMemsetAsync(cnt, 0, (size_t)(N + 136) * sizeof(int), stream);

    // count ∥ encoder(+self-fold l0) ∥ fold(l1,l2)
    countenc_kernel<<<nblkE + nEnc + 4, 256, 0, stream>>>(
        ei, x, Wenc1, benc1, Wenc2, benc2,
        Wg[0], as_[0], ad_[0], Wg[1], as_[1], ad_[1], Wg[2], as_[2], ad_[2],
        cnt, vfold, buf0, asrc, adst, N, E, nblkE, nEnc);

    // scan + fill (single launch, load-only release polling)
    scanfill_kernel<<<nscan + nblkE, 256, 0, stream>>>(
        ei, cnt, ready, sdone, rowptr, cursor, col, N, E);

    // 3 GAT layers (unchanged R8 kernels)
    float* bin = buf0;
    float* bout = buf1;
    for (int l = 0; l < 3; ++l) {
        gat_agg_kernel<<<(N + 15) / 16, 256, 0, stream>>>(bin, asrc, adst, rowptr, col,
                                                          g, N);
        const int has_next = (l < 2) ? 1 : 0;
        gat_post_kernel<<<(N + 63) / 64, 256, 0, stream>>>(
            g, Wg[l], bg[l], bin, vfold + (l + 1 < 3 ? (l + 1) * 512 : 0), has_next,
            bout, asrc, adst,
            Wo1, bo1, Wo2, bo2, Wo3, bo3, (float*)d_out, N);
        float* tmp = bin; bin = bout; bout = tmp;
    }
}

// Round 11
// 293.264 us; speedup vs baseline: 6.2268x; 1.2273x over previous
//
#include <hip/hip_runtime.h>
#include <cstdint>
#include <cstddef>

#define NEG_SLOPE 0.2f

__device__ __forceinline__ float elu_f(float x) {
    return x > 0.f ? x : expm1f(x);
}

// ---------------------------------------------------------------------------
// countenc: disjoint block ranges, independent work (no cross-block deps).
//   blocks [0, nblkE):          degree count (self-detects int64 layout)
//   blocks [nblkE, nblkE+nEnc): encoder 64-node LDS GEMM + self-folded
//                               layer-0 attention dots
//   blocks [nblkE+nEnc, +4):    fold vfold for layers 1,2
// ---------------------------------------------------------------------------
#define H1STR 68
__global__ __launch_bounds__(256) void countenc_kernel(
    const int* __restrict__ ei, const float* __restrict__ x,
    const float* __restrict__ Wenc1, const float* __restrict__ benc1,
    const float* __restrict__ Wenc2, const float* __restrict__ benc2,
    const float* __restrict__ Wg0, const float* __restrict__ as0,
    const float* __restrict__ ad0,
    const float* __restrict__ Wg1, const float* __restrict__ as1,
    const float* __restrict__ ad1,
    const float* __restrict__ Wg2, const float* __restrict__ as2,
    const float* __restrict__ ad2,
    int* __restrict__ cnt, float* __restrict__ vfold,
    float* __restrict__ h0, float* __restrict__ asrc, float* __restrict__ adst,
    int N, int E, int nblkE, int nEnc) {
    const int b = blockIdx.x, t = threadIdx.x;
    const int Etot = E + N;

    __shared__ float W1s[256];
    __shared__ float b1s[32];
    __shared__ float b2s[64];
    __shared__ float vsd[512];
    __shared__ float xS[512];
    __shared__ float W2s[2048];
    __shared__ float h1T[32 * H1STR];
    __shared__ int sflag;

    // ---- count path ----
    if (b < nblkE) {
        if (t == 0) {
            int acc = 0;
#pragma unroll
            for (int k = 0; k < 8; ++k) acc |= ei[2 * k + 1];
            sflag = (acc == 0) ? 1 : 0;
        }
        __syncthreads();
        const int e = b * 256 + t;
        if (e < Etot) {
            int d;
            if (e < E) d = sflag ? ei[2 * (size_t)(E + e)] : ei[E + e];
            else       d = e - E;  // self loop
            atomicAdd(&cnt[d], 1);
        }
        return;
    }
    // ---- fold path (layers 1,2) ----
    if (b >= nblkE + nEnc) {
        const int e = (b - nblkE - nEnc) * 256 + t;
        if (e < 1024) {
            const int l = 1 + (e >> 9), rem = e & 511;
            const int k = rem >> 3, j = rem & 7, h = j & 3;
            const float* W   = (l == 1) ? Wg1 : Wg2;
            const float* asl = (l == 1) ? as1 : as2;
            const float* adl = (l == 1) ? ad1 : ad2;
            const float* av = (j < 4) ? asl : adl;
            const float* wr = W + k * 256 + h * 64;
            const float* ar = av + h * 64;
            float s = 0.f;
#pragma unroll 8
            for (int cc = 0; cc < 64; ++cc) s += wr[cc] * ar[cc];
            vfold[l * 512 + k * 8 + j] = s;
        }
        return;
    }

    // ---- encoder path ----
    const int n0 = (b - nblkE) * 64;
    const int rem = N - n0;
    *(float4*)(W2s + t * 4) = *(const float4*)(Wenc2 + t * 4);
    *(float4*)(W2s + 1024 + t * 4) = *(const float4*)(Wenc2 + 1024 + t * 4);
    if (t < 64)  *(float4*)(W1s + t * 4) = *(const float4*)(Wenc1 + t * 4);
    if (t < 8)   *(float4*)(b1s + t * 4) = *(const float4*)(benc1 + t * 4);
    if (t < 16)  *(float4*)(b2s + t * 4) = *(const float4*)(benc2 + t * 4);
    if (t < 128) {
        const int fidx = t * 4;
        float4 v = make_float4(0.f, 0.f, 0.f, 0.f);
        if (fidx < rem * 8) v = *(const float4*)(x + (size_t)n0 * 8 + fidx);
        *(float4*)(xS + fidx) = v;
    }
    // self-fold layer-0 attention vectors into vsd
#pragma unroll
    for (int u = 0; u < 2; ++u) {
        const int e2 = t * 2 + u;
        const int k = e2 >> 3, j = e2 & 7, h = j & 3;
        const float* av = (j < 4) ? as0 : ad0;
        const float* wr = Wg0 + k * 256 + h * 64;
        const float* ar = av + h * 64;
        float s = 0.f;
#pragma unroll 8
        for (int cc = 0; cc < 64; ++cc) s += wr[cc] * ar[cc];
        vsd[k * 8 + j] = s;
    }
    __syncthreads();
    {   // phase A: h1 = elu(x@W1+b1) -> h1T
        const int nl = t >> 2;
        const int j0 = (t & 3) * 8;
        const float4 xa = *(const float4*)(xS + nl * 8);
        const float4 xb = *(const float4*)(xS + nl * 8 + 4);
        const float xk[8] = {xa.x, xa.y, xa.z, xa.w, xb.x, xb.y, xb.z, xb.w};
        float a[8];
#pragma unroll
        for (int u = 0; u < 8; ++u) a[u] = b1s[j0 + u];
#pragma unroll
        for (int k = 0; k < 8; ++k) {
            const float4 w0 = *(const float4*)(W1s + k * 32 + j0);
            const float4 w1 = *(const float4*)(W1s + k * 32 + j0 + 4);
            a[0] += xk[k] * w0.x; a[1] += xk[k] * w0.y;
            a[2] += xk[k] * w0.z; a[3] += xk[k] * w0.w;
            a[4] += xk[k] * w1.x; a[5] += xk[k] * w1.y;
            a[6] += xk[k] * w1.z; a[7] += xk[k] * w1.w;
        }
#pragma unroll
        for (int u = 0; u < 8; ++u) h1T[(j0 + u) * H1STR + nl] = elu_f(a[u]);
    }
    __syncthreads();
    {   // phase B: h0 = elu(h1@W2+b2) + fused layer-0 dots
        const int cg = t & 15;
        const int nq = t >> 4;
        const int c0 = cg * 4;
        float acc[4][4];
#pragma unroll
        for (int i = 0; i < 4; ++i)
#pragma unroll
            for (int c = 0; c < 4; ++c) acc[i][c] = b2s[c0 + c];
#pragma unroll 8
        for (int k = 0; k < 32; ++k) {
            const float4 hv = *(const float4*)(h1T + k * H1STR + nq * 4);
            const float4 wv = *(const float4*)(W2s + k * 64 + c0);
            const float hvv[4] = {hv.x, hv.y, hv.z, hv.w};
#pragma unroll
            for (int i = 0; i < 4; ++i) {
                acc[i][0] += hvv[i] * wv.x; acc[i][1] += hvv[i] * wv.y;
                acc[i][2] += hvv[i] * wv.z; acc[i][3] += hvv[i] * wv.w;
            }
        }
        float o[4][4];
#pragma unroll
        for (int i = 0; i < 4; ++i)
#pragma unroll
            for (int c = 0; c < 4; ++c) o[i][c] = elu_f(acc[i][c]);
#pragma unroll
        for (int i = 0; i < 4; ++i) {
            const int n = n0 + nq * 4 + i;
            if (n < N)
                *(float4*)(h0 + (size_t)n * 64 + c0) =
                    make_float4(o[i][0], o[i][1], o[i][2], o[i][3]);
        }
        float ad[4][8];
#pragma unroll
        for (int i = 0; i < 4; ++i)
#pragma unroll
            for (int jj = 0; jj < 8; ++jj) ad[i][jj] = 0.f;
#pragma unroll
        for (int c = 0; c < 4; ++c) {
            const float4 v0 = *(const float4*)(vsd + (c0 + c) * 8);
            const float4 v1 = *(const float4*)(vsd + (c0 + c) * 8 + 4);
#pragma unroll
            for (int i = 0; i < 4; ++i) {
                ad[i][0] += o[i][c] * v0.x; ad[i][1] += o[i][c] * v0.y;
                ad[i][2] += o[i][c] * v0.z; ad[i][3] += o[i][c] * v0.w;
                ad[i][4] += o[i][c] * v1.x; ad[i][5] += o[i][c] * v1.y;
                ad[i][6] += o[i][c] * v1.z; ad[i][7] += o[i][c] * v1.w;
            }
        }
#pragma unroll
        for (int off = 1; off < 16; off <<= 1) {
#pragma unroll
            for (int i = 0; i < 4; ++i)
#pragma unroll
                for (int jj = 0; jj < 8; ++jj)
                    ad[i][jj] += __shfl_xor(ad[i][jj], off);
        }
        if (cg == 0) {
#pragma unroll
            for (int i = 0; i < 4; ++i) {
                const int n = n0 + nq * 4 + i;
                if (n < N) {
#pragma unroll
                    for (int h = 0; h < 4; ++h) {
                        asrc[n * 4 + h] = ad[i][h];
                        adst[n * 4 + h] = ad[i][4 + h];
                    }
                }
            }
        }
    }
}

// ---------------------------------------------------------------------------
// One-pass scan with parallel lookback (79 co-resident blocks) — R8-proven.
// ---------------------------------------------------------------------------
#define SCAN_B 256
__global__ __launch_bounds__(256) void scan_onepass_kernel(
    const int* __restrict__ cnt, int* __restrict__ ready,
    int* __restrict__ rowptr, int* __restrict__ cursor, int n) {
    __shared__ int sd[SCAN_B];
    __shared__ int sred[128];
    __shared__ int s_pref;
    const int b = blockIdx.x, t = threadIdx.x;
    const int g = b * SCAN_B + t;
    const int v = (g < n) ? cnt[g] : 0;
    sd[t] = v;
    __syncthreads();
    for (int off = 1; off < SCAN_B; off <<= 1) {
        int add = (t >= off) ? sd[t - off] : 0;
        __syncthreads();
        sd[t] += add;
        __syncthreads();
    }
    if (t == SCAN_B - 1) atomicExch(&ready[b], sd[SCAN_B - 1] + 1);
    if (t < 128) {
        int pv = 0;
        if (t < b) {
            do { pv = atomicAdd(&ready[t], 0); __builtin_amdgcn_s_sleep(1); } while (pv == 0);
            pv -= 1;
        }
        sred[t] = pv;
    }
    __syncthreads();
    if (t == 0) {
        int s = 0;
#pragma unroll 8
        for (int i = 0; i < 128; ++i) s += sred[i];
        s_pref = s;
    }
    __syncthreads();
    const int pre = s_pref;
    if (g < n) {
        const int e = pre + sd[t];
        rowptr[g + 1] = e;
        cursor[g] = e - v;
        if (g == 0) rowptr[0] = 0;
    }
}

__global__ void fill_kernel(const int* __restrict__ ei, int E, int Etot,
                            int* __restrict__ cursor, int* __restrict__ col) {
    __shared__ int sflag;
    const int t = threadIdx.x;
    if (t == 0) {
        int acc = 0;
#pragma unroll
        for (int k = 0; k < 8; ++k) acc |= ei[2 * k + 1];
        sflag = (acc == 0) ? 1 : 0;
    }
    __syncthreads();
    int e = blockIdx.x * blockDim.x + t;
    if (e >= Etot) return;
    int s, d;
    if (e < E) {
        if (sflag) { s = ei[2 * (size_t)e]; d = ei[2 * (size_t)(E + e)]; }
        else       { s = ei[e];             d = ei[E + e]; }
    } else {
        s = d = e - E;
    }
    int pos = atomicAdd(&cursor[d], 1);
    col[pos] = s;
}

// ---------------------------------------------------------------------------
// GAT aggregation: one 16-lane group per dst node (4 nodes/wave, 16/block).
// ---------------------------------------------------------------------------
__global__ __launch_bounds__(256) void gat_agg_kernel(
    const float* __restrict__ bin, const float* __restrict__ asrc,
    const float* __restrict__ adst, const int* __restrict__ rowptr,
    const int* __restrict__ col, float* __restrict__ g, int n_nodes) {
    const int grp = threadIdx.x >> 4;
    const int q = threadIdx.x & 15;
    const int n = blockIdx.x * 16 + grp;
    if (n >= n_nodes) return;
    const float4 ad4 = *(const float4*)(adst + (size_t)n * 4);
    const int start = rowptr[n], end = rowptr[n + 1];

    float acc[4][4];
#pragma unroll
    for (int h = 0; h < 4; ++h)
#pragma unroll
        for (int z = 0; z < 4; ++z) acc[h][z] = 0.f;
    float4 den4 = make_float4(0.f, 0.f, 0.f, 0.f);

    for (int base = start; base < end; base += 16) {
        const int cnt2 = min(16, end - base);
        int c = 0;
        float4 w4 = make_float4(0.f, 0.f, 0.f, 0.f);
        if (base + q < end) {
            c = col[base + q];
            const float4 av = *(const float4*)(asrc + (size_t)c * 4);
            float l0 = av.x + ad4.x; l0 = l0 > 0.f ? l0 : NEG_SLOPE * l0;
            float l1 = av.y + ad4.y; l1 = l1 > 0.f ? l1 : NEG_SLOPE * l1;
            float l2 = av.z + ad4.z; l2 = l2 > 0.f ? l2 : NEG_SLOPE * l2;
            float l3 = av.w + ad4.w; l3 = l3 > 0.f ? l3 : NEG_SLOPE * l3;
            w4.x = __expf(fminf(l0, 60.f));
            w4.y = __expf(fminf(l1, 60.f));
            w4.z = __expf(fminf(l2, 60.f));
            w4.w = __expf(fminf(l3, 60.f));
            den4.x += w4.x; den4.y += w4.y; den4.z += w4.z; den4.w += w4.w;
        }
        int j = 0;
        for (; j + 4 <= cnt2; j += 4) {
#pragma unroll
            for (int u = 0; u < 4; ++u) {
                const int s = __shfl(c, j + u, 16);
                const float4 hv = *(const float4*)(bin + (size_t)s * 64 + q * 4);
                const float wx = __shfl(w4.x, j + u, 16);
                const float wy = __shfl(w4.y, j + u, 16);
                const float wz = __shfl(w4.z, j + u, 16);
                const float ww = __shfl(w4.w, j + u, 16);
                acc[0][0] += wx * hv.x; acc[0][1] += wx * hv.y;
                acc[0][2] += wx * hv.z; acc[0][3] += wx * hv.w;
                acc[1][0] += wy * hv.x; acc[1][1] += wy * hv.y;
                acc[1][2] += wy * hv.z; acc[1][3] += wy * hv.w;
                acc[2][0] += wz * hv.x; acc[2][1] += wz * hv.y;
                acc[2][2] += wz * hv.z; acc[2][3] += wz * hv.w;
                acc[3][0] += ww * hv.x; acc[3][1] += ww * hv.y;
                acc[3][2] += ww * hv.z; acc[3][3] += ww * hv.w;
            }
        }
        for (; j < cnt2; ++j) {
            const int s = __shfl(c, j, 16);
            const float4 hv = *(const float4*)(bin + (size_t)s * 64 + q * 4);
            const float wx = __shfl(w4.x, j, 16);
            const float wy = __shfl(w4.y, j, 16);
            const float wz = __shfl(w4.z, j, 16);
            const float ww = __shfl(w4.w, j, 16);
            acc[0][0] += wx * hv.x; acc[0][1] += wx * hv.y;
            acc[0][2] += wx * hv.z; acc[0][3] += wx * hv.w;
            acc[1][0] += wy * hv.x; acc[1][1] += wy * hv.y;
            acc[1][2] += wy * hv.z; acc[1][3] += wy * hv.w;
            acc[2][0] += wz * hv.x; acc[2][1] += wz * hv.y;
            acc[2][2] += wz * hv.z; acc[2][3] += wz * hv.w;
            acc[3][0] += ww * hv.x; acc[3][1] += ww * hv.y;
            acc[3][2] += ww * hv.z; acc[3][3] += ww * hv.w;
        }
    }
#pragma unroll
    for (int off = 1; off < 16; off <<= 1) {
        den4.x += __shfl_xor(den4.x, off, 16);
        den4.y += __shfl_xor(den4.y, off, 16);
        den4.z += __shfl_xor(den4.z, off, 16);
        den4.w += __shfl_xor(den4.w, off, 16);
    }
    const float i0 = 1.f / (den4.x + 1e-16f);
    const float i1 = 1.f / (den4.y + 1e-16f);
    const float i2 = 1.f / (den4.z + 1e-16f);
    const float i3 = 1.f / (den4.w + 1e-16f);
    float* gr = g + (size_t)n * 256 + q * 4;
    *(float4*)(gr +   0) = make_float4(acc[0][0]*i0, acc[0][1]*i0, acc[0][2]*i0, acc[0][3]*i0);
    *(float4*)(gr +  64) = make_float4(acc[1][0]*i1, acc[1][1]*i1, acc[1][2]*i1, acc[1][3]*i1);
    *(float4*)(gr + 128) = make_float4(acc[2][0]*i2, acc[2][1]*i2, acc[2][2]*i2, acc[2][3]*i2);
    *(float4*)(gr + 192) = make_float4(acc[3][0]*i3, acc[3][1]*i3, acc[3][2]*i3, acc[3][3]*i3);
}

// ---------------------------------------------------------------------------
// GAT post-projection. has_next=1: fused next-layer dots. has_next=0: fused
// output MLP 64->64->32->8, writes d_out directly.
// ---------------------------------------------------------------------------
#define GSTR 132
__global__ __launch_bounds__(256) void gat_post_kernel(
    const float* __restrict__ g, const float* __restrict__ W,
    const float* __restrict__ bias, const float* __restrict__ xin,
    const float* __restrict__ vfold_next, int has_next,
    float* __restrict__ out, float* __restrict__ asrc, float* __restrict__ adst,
    const float* __restrict__ Wm1, const float* __restrict__ bm1,
    const float* __restrict__ Wm2, const float* __restrict__ bm2,
    const float* __restrict__ Wm3, const float* __restrict__ bm3,
    float* __restrict__ mlp_out, int n_nodes) {
    __shared__ float gS[64 * GSTR];
    __shared__ float Wp[128 * 64];
    __shared__ float vN[512];
    const int t = threadIdx.x;
    const int n0 = blockIdx.x * 64;
    const int cg = t & 7;
    const int ng = t >> 3;

    if (has_next && t < 128) *(float4*)(vN + t * 4) = *(const float4*)(vfold_next + t * 4);

    float acc[2][8];
#pragma unroll
    for (int i = 0; i < 2; ++i)
#pragma unroll
        for (int qq = 0; qq < 8; ++qq) acc[i][qq] = 0.f;

    for (int slab = 0; slab < 2; ++slab) {
        __syncthreads();
#pragma unroll
        for (int j = 0; j < 8; ++j) {
            const int idx = j * 256 + t;
            const int nl = idx >> 5;
            const int c4 = idx & 31;
            float4 v = make_float4(0.f, 0.f, 0.f, 0.f);
            if (n0 + nl < n_nodes)
                v = *(const float4*)(g + (size_t)(n0 + nl) * 256 + slab * 128 + c4 * 4);
            *(float4*)(gS + nl * GSTR + c4 * 4) = v;
        }
#pragma unroll
        for (int j = 0; j < 8; ++j) {
            const int f4 = j * 256 + t;
            const int kl = f4 >> 4;
            const int kap = slab * 128 + kl;
            const int h = kap >> 6, kk = kap & 63;
            const int c = (f4 & 15) * 4;
            *(float4*)(Wp + kl * 64 + c) = *(const float4*)(W + kk * 256 + h * 64 + c);
        }
        __syncthreads();
#pragma unroll 4
        for (int kl = 0; kl < 128; ++kl) {
            const float a0 = gS[(ng * 2 + 0) * GSTR + kl];
            const float a1 = gS[(ng * 2 + 1) * GSTR + kl];
            const float4 b0 = *(const float4*)(Wp + kl * 64 + cg * 8);
            const float4 b1 = *(const float4*)(Wp + kl * 64 + cg * 8 + 4);
            acc[0][0] += a0 * b0.x; acc[0][1] += a0 * b0.y;
            acc[0][2] += a0 * b0.z; acc[0][3] += a0 * b0.w;
            acc[0][4] += a0 * b1.x; acc[0][5] += a0 * b1.y;
            acc[0][6] += a0 * b1.z; acc[0][7] += a0 * b1.w;
            acc[1][0] += a1 * b0.x; acc[1][1] += a1 * b0.y;
            acc[1][2] += a1 * b0.z; acc[1][3] += a1 * b0.w;
            acc[1][4] += a1 * b1.x; acc[1][5] += a1 * b1.y;
            acc[1][6] += a1 * b1.z; acc[1][7] += a1 * b1.w;
        }
    }

    const int c0 = cg * 8;
    const float4 bb0 = *(const float4*)(bias + c0);
    const float4 bb1 = *(const float4*)(bias + c0 + 4);
    float o[2][8];
#pragma unroll
    for (int i = 0; i < 2; ++i) {
        const int n = n0 + ng * 2 + i;
        if (n < n_nodes) {
            const float4 x0 = *(const float4*)(xin + (size_t)n * 64 + c0);
            const float4 x1 = *(const float4*)(xin + (size_t)n * 64 + c0 + 4);
            o[i][0] = 0.25f * acc[i][0] + bb0.x + x0.x;
            o[i][1] = 0.25f * acc[i][1] + bb0.y + x0.y;
            o[i][2] = 0.25f * acc[i][2] + bb0.z + x0.z;
            o[i][3] = 0.25f * acc[i][3] + bb0.w + x0.w;
            o[i][4] = 0.25f * acc[i][4] + bb1.x + x1.x;
            o[i][5] = 0.25f * acc[i][5] + bb1.y + x1.y;
            o[i][6] = 0.25f * acc[i][6] + bb1.z + x1.z;
            o[i][7] = 0.25f * acc[i][7] + bb1.w + x1.w;
            if (has_next) {
                *(float4*)(out + (size_t)n * 64 + c0) =
                    make_float4(o[i][0], o[i][1], o[i][2], o[i][3]);
                *(float4*)(out + (size_t)n * 64 + c0 + 4) =
                    make_float4(o[i][4], o[i][5], o[i][6], o[i][7]);
            }
        } else {
#pragma unroll
            for (int qq = 0; qq < 8; ++qq) o[i][qq] = 0.f;
        }
    }

    if (has_next) {
        float pj[2][8];
#pragma unroll
        for (int i = 0; i < 2; ++i)
#pragma unroll
            for (int jj = 0; jj < 8; ++jj) pj[i][jj] = 0.f;
#pragma unroll
        for (int cidx = 0; cidx < 8; ++cidx) {
#pragma unroll
            for (int jj = 0; jj < 8; ++jj) {
                const float vv = vN[(c0 + cidx) * 8 + jj];
                pj[0][jj] += o[0][cidx] * vv;
                pj[1][jj] += o[1][cidx] * vv;
            }
        }
#pragma unroll
        for (int off = 1; off < 8; off <<= 1) {
#pragma unroll
            for (int i = 0; i < 2; ++i)
#pragma unroll
                for (int jj = 0; jj < 8; ++jj)
                    pj[i][jj] += __shfl_xor(pj[i][jj], off);
        }
        if (cg == 0) {
#pragma unroll
            for (int i = 0; i < 2; ++i) {
                const int n = n0 + ng * 2 + i;
                if (n < n_nodes) {
#pragma unroll
                    for (int h = 0; h < 4; ++h) {
                        asrc[n * 4 + h] = pj[i][h];
                        adst[n * 4 + h] = pj[i][4 + h];
                    }
                }
            }
        }
        return;
    }

    // ---- fused output MLP (last layer) ----
    __syncthreads();
#pragma unroll
    for (int i = 0; i < 2; ++i) {
        const int nl = ng * 2 + i;
        *(float4*)(gS + nl * GSTR + c0)     = make_float4(o[i][0], o[i][1], o[i][2], o[i][3]);
        *(float4*)(gS + nl * GSTR + c0 + 4) = make_float4(o[i][4], o[i][5], o[i][6], o[i][7]);
    }
    {
#pragma unroll
        for (int j = 0; j < 4; ++j)
            *(float4*)(Wp + (j * 256 + t) * 4) = *(const float4*)(Wm1 + (j * 256 + t) * 4);
#pragma unroll
        for (int j = 0; j < 2; ++j)
            *(float4*)(Wp + 4096 + (j * 256 + t) * 4) = *(const float4*)(Wm2 + (j * 256 + t) * 4);
        if (t < 64) vN[t] = bm1[t];
        else if (t < 96) vN[t] = bm2[t - 64];
        else if (t < 104) vN[t] = bm3[t - 96];
        vN[104 + t] = Wm3[t];
    }
    __syncthreads();
    {
        float a1[2][8];
#pragma unroll
        for (int i = 0; i < 2; ++i)
#pragma unroll
            for (int qq = 0; qq < 8; ++qq) a1[i][qq] = vN[c0 + qq];
#pragma unroll 4
        for (int k = 0; k < 64; ++k) {
            const float h0 = gS[(ng * 2 + 0) * GSTR + k];
            const float h1v = gS[(ng * 2 + 1) * GSTR + k];
            const float4 w0 = *(const float4*)(Wp + k * 64 + c0);
            const float4 w1 = *(const float4*)(Wp + k * 64 + c0 + 4);
            a1[0][0] += h0 * w0.x; a1[0][1] += h0 * w0.y;
            a1[0][2] += h0 * w0.z; a1[0][3] += h0 * w0.w;
            a1[0][4] += h0 * w1.x; a1[0][5] += h0 * w1.y;
            a1[0][6] += h0 * w1.z; a1[0][7] += h0 * w1.w;
            a1[1][0] += h1v * w0.x; a1[1][1] += h1v * w0.y;
            a1[1][2] += h1v * w0.z; a1[1][3] += h1v * w0.w;
            a1[1][4] += h1v * w1.x; a1[1][5] += h1v * w1.y;
            a1[1][6] += h1v * w1.z; a1[1][7] += h1v * w1.w;
        }
#pragma unroll
        for (int i = 0; i < 2; ++i) {
            const int nl = ng * 2 + i;
            float4 v0 = make_float4(elu_f(a1[i][0]), elu_f(a1[i][1]), elu_f(a1[i][2]), elu_f(a1[i][3]));
            float4 v1 = make_float4(elu_f(a1[i][4]), elu_f(a1[i][5]), elu_f(a1[i][6]), elu_f(a1[i][7]));
            *(float4*)(gS + nl * GSTR + 64 + c0)     = v0;
            *(float4*)(gS + nl * GSTR + 64 + c0 + 4) = v1;
        }
    }
    __syncthreads();
    {
        const int cg4 = t & 3;
        const int nn = t >> 2;
        const int cc0 = cg4 * 8;
        float a2[8];
#pragma unroll
        for (int qq = 0; qq < 8; ++qq) a2[qq] = vN[64 + cc0 + qq];
#pragma unroll 4
        for (int j = 0; j < 64; ++j) {
            const float ov = gS[nn * GSTR + 64 + j];
            const float4 w0 = *(const float4*)(Wp + 4096 + j * 32 + cc0);
            const float4 w1 = *(const float4*)(Wp + 4096 + j * 32 + cc0 + 4);
            a2[0] += ov * w0.x; a2[1] += ov * w0.y;
            a2[2] += ov * w0.z; a2[3] += ov * w0.w;
            a2[4] += ov * w1.x; a2[5] += ov * w1.y;
            a2[6] += ov * w1.z; a2[7] += ov * w1.w;
        }
        __syncthreads();
        *(float4*)(gS + nn * GSTR + cc0)     = make_float4(elu_f(a2[0]), elu_f(a2[1]), elu_f(a2[2]), elu_f(a2[3]));
        *(float4*)(gS + nn * GSTR + cc0 + 4) = make_float4(elu_f(a2[4]), elu_f(a2[5]), elu_f(a2[6]), elu_f(a2[7]));
    }
    __syncthreads();
    {
        const int c3 = t & 7;
        const int nq = t >> 3;
#pragma unroll
        for (int i = 0; i < 2; ++i) {
            const int nl = nq * 2 + i;
            const int n = n0 + nl;
            if (n >= n_nodes) continue;
            float a3 = vN[96 + c3];
#pragma unroll 4
            for (int j = 0; j < 32; ++j)
                a3 += gS[nl * GSTR + j] * vN[104 + j * 8 + c3];
            mlp_out[(size_t)n * 8 + c3] = a3;
        }
    }
}

// ---------------------------------------------------------------------------
extern "C" void kernel_launch(void* const* d_in, const int* in_sizes, int n_in,
                              void* d_out, int out_size, void* d_ws, size_t ws_size,
                              hipStream_t stream) {
    const float* x     = (const float*)d_in[0];
    const int*   ei    = (const int*)d_in[1];
    const float* Wenc1 = (const float*)d_in[2];
    const float* benc1 = (const float*)d_in[3];
    const float* Wenc2 = (const float*)d_in[4];
    const float* benc2 = (const float*)d_in[5];
    const float* Wg[3]  = {(const float*)d_in[6],  (const float*)d_in[10], (const float*)d_in[14]};
    const float* as_[3] = {(const float*)d_in[7],  (const float*)d_in[11], (const float*)d_in[15]};
    const float* ad_[3] = {(const float*)d_in[8],  (const float*)d_in[12], (const float*)d_in[16]};
    const float* bg[3]  = {(const float*)d_in[9],  (const float*)d_in[13], (const float*)d_in[17]};
    const float* Wo1 = (const float*)d_in[18];
    const float* bo1 = (const float*)d_in[19];
    const float* Wo2 = (const float*)d_in[20];
    const float* bo2 = (const float*)d_in[21];
    const float* Wo3 = (const float*)d_in[22];
    const float* bo3 = (const float*)d_in[23];

    const int N = in_sizes[0] / 8;
    const int E = in_sizes[1] / 2;
    const int Etot = E + N;
    const int nblkE = (Etot + 255) / 256;
    const int nEnc  = (N + 63) / 64;
    const int nscan = (N + 255) / 256;

    float* buf0  = (float*)d_ws;                  // N*64
    float* buf1  = buf0 + (size_t)N * 64;         // N*64
    float* g     = buf1 + (size_t)N * 64;         // N*256
    float* asrc  = g + (size_t)N * 256;           // N*4
    float* adst  = asrc + (size_t)N * 4;          // N*4
    float* vfold = adst + (size_t)N * 4;          // 3*512
    int* rowptr = (int*)(vfold + 3 * 512);        // N+1 (+pad)
    int* cursor = rowptr + (N + 2);               // N
    int* cnt    = cursor + N;                     // N    <- memset region start
    int* ready  = cnt + N;                        // 128
    int* col    = ready + 128;                    // Etot

    // zero cnt + ready in one async memset (graph-capturable)
    hipMemsetAsync(cnt, 0, (size_t)(N + 128) * sizeof(int), stream);

    // count ∥ encoder(+self-fold l0) ∥ fold(l1,l2)
    countenc_kernel<<<nblkE + nEnc + 4, 256, 0, stream>>>(
        ei, x, Wenc1, benc1, Wenc2, benc2,
        Wg[0], as_[0], ad_[0], Wg[1], as_[1], ad_[1], Wg[2], as_[2], ad_[2],
        cnt, vfold, buf0, asrc, adst, N, E, nblkE, nEnc);

    // scan, then fill (separate launches — R10's merged version serialized on
    // 1300 spinning blocks; stream boundary is cheaper than intra-grid sync)
    scan_onepass_kernel<<<nscan, SCAN_B, 0, stream>>>(cnt, ready, rowptr, cursor, N);
    fill_kernel<<<nblkE, 256, 0, stream>>>(ei, E, Etot, cursor, col);

    // 3 GAT layers
    float* bin = buf0;
    float* bout = buf1;
    for (int l = 0; l < 3; ++l) {
        gat_agg_kernel<<<(N + 15) / 16, 256, 0, stream>>>(bin, asrc, adst, rowptr, col,
                                                          g, N);
        const int has_next = (l < 2) ? 1 : 0;
        gat_post_kernel<<<(N + 63) / 64, 256, 0, stream>>>(
            g, Wg[l], bg[l], bin, vfold + (l + 1 < 3 ? (l + 1) * 512 : 0), has_next,
            bout, asrc, adst,
            Wo1, bo1, Wo2, bo2, Wo3, bo3, (float*)d_out, N);
        float* tmp = bin; bin = bout; bout = tmp;
    }
}

// Round 12
// 290.993 us; speedup vs baseline: 6.2754x; 1.0078x over previous
//
#include <hip/hip_runtime.h>
#include <cstdint>
#include <cstddef>

#define NEG_SLOPE 0.2f

__device__ __forceinline__ float elu_f(float x) {
    return x > 0.f ? x : expm1f(x);
}

// ---------------------------------------------------------------------------
// P0: zero cnt + ready, detect edge-index layout, compute folded attention
// vectors for all 3 layers. Blocks 0..78 zero; blocks 79..84 fold.
// vfold[l][k*8+j] = sum_cc W_l[k, h*64+cc]*att[h,cc] (j<4 src, j>=4 dst, h=j&3)
// ---------------------------------------------------------------------------
__global__ __launch_bounds__(256) void prep_kernel(
    const int* __restrict__ ei,
    const float* __restrict__ W0, const float* __restrict__ as0, const float* __restrict__ ad0,
    const float* __restrict__ W1, const float* __restrict__ as1, const float* __restrict__ ad1,
    const float* __restrict__ W2, const float* __restrict__ as2, const float* __restrict__ ad2,
    int* __restrict__ cnt, int* __restrict__ ready, int* __restrict__ flag,
    float* __restrict__ vfold, int n) {
    const int b = blockIdx.x, t = threadIdx.x;
    if (b < 79) {
        const int i = b * 256 + t;
        if (i < n) cnt[i] = 0;
        if (b == 0) {
            if (t < 128) ready[t] = 0;
            if (t == 0) {
                int acc = 0;
#pragma unroll
                for (int k = 0; k < 8; ++k) acc |= ei[2 * k + 1];
                flag[0] = (acc == 0) ? 1 : 0;
            }
        }
        return;
    }
    const int e = (b - 79) * 256 + t;
    if (e >= 1536) return;
    const int l = e >> 9, rem = e & 511;
    const int k = rem >> 3, j = rem & 7, h = j & 3;
    const float* W   = (l == 0) ? W0  : (l == 1) ? W1  : W2;
    const float* as_ = (l == 0) ? as0 : (l == 1) ? as1 : as2;
    const float* ad_ = (l == 0) ? ad0 : (l == 1) ? ad1 : ad2;
    const float* av = (j < 4) ? as_ : ad_;
    const float* wr = W + k * 256 + h * 64;
    const float* ar = av + h * 64;
    float s = 0.f;
#pragma unroll 8
    for (int cc = 0; cc < 64; ++cc) s += wr[cc] * ar[cc];
    vfold[l * 512 + k * 8 + j] = s;
}

__global__ void count_kernel(const int* __restrict__ ei, const int* __restrict__ flag,
                             int E, int Etot, int* __restrict__ cnt) {
    int e = blockIdx.x * blockDim.x + threadIdx.x;
    if (e >= Etot) return;
    int d;
    if (e < E) d = flag[0] ? ei[2 * (size_t)(E + e)] : ei[E + e];
    else       d = e - E;  // self loop
    atomicAdd(&cnt[d], 1);
}

// ---------------------------------------------------------------------------
// One-pass scan with parallel lookback (79 co-resident blocks).
// ---------------------------------------------------------------------------
#define SCAN_B 256
__global__ __launch_bounds__(256) void scan_onepass_kernel(
    const int* __restrict__ cnt, int* __restrict__ ready,
    int* __restrict__ rowptr, int* __restrict__ cursor, int n) {
    __shared__ int sd[SCAN_B];
    __shared__ int sred[128];
    __shared__ int s_pref;
    const int b = blockIdx.x, t = threadIdx.x;
    const int g = b * SCAN_B + t;
    const int v = (g < n) ? cnt[g] : 0;
    sd[t] = v;
    __syncthreads();
    for (int off = 1; off < SCAN_B; off <<= 1) {
        int add = (t >= off) ? sd[t - off] : 0;
        __syncthreads();
        sd[t] += add;
        __syncthreads();
    }
    if (t == SCAN_B - 1) atomicExch(&ready[b], sd[SCAN_B - 1] + 1);
    if (t < 128) {
        int pv = 0;
        if (t < b) {
            do { pv = atomicAdd(&ready[t], 0); __builtin_amdgcn_s_sleep(1); } while (pv == 0);
            pv -= 1;
        }
        sred[t] = pv;
    }
    __syncthreads();
    if (t == 0) {
        int s = 0;
#pragma unroll 8
        for (int i = 0; i < 128; ++i) s += sred[i];
        s_pref = s;
    }
    __syncthreads();
    const int pre = s_pref;
    if (g < n) {
        const int e = pre + sd[t];
        rowptr[g + 1] = e;
        cursor[g] = e - v;
        if (g == 0) rowptr[0] = 0;
    }
}

__global__ void fill_kernel(const int* __restrict__ ei, const int* __restrict__ flag,
                            int E, int Etot, int* __restrict__ cursor,
                            int* __restrict__ col) {
    int e = blockIdx.x * blockDim.x + threadIdx.x;
    if (e >= Etot) return;
    int s, d;
    if (e < E) {
        if (flag[0]) { s = ei[2 * (size_t)e]; d = ei[2 * (size_t)(E + e)]; }
        else         { s = ei[e];             d = ei[E + e]; }
    } else {
        s = d = e - E;
    }
    int pos = atomicAdd(&cursor[d], 1);
    col[pos] = s;
}

// ---------------------------------------------------------------------------
// Encoder v2: LDS-tiled GEMM, 64 nodes/block (313 blocks), + layer-0 dots.
// ---------------------------------------------------------------------------
#define H1STR 68
__global__ __launch_bounds__(256) void encoder_kernel(
    const float* __restrict__ x,
    const float* __restrict__ W1, const float* __restrict__ b1,
    const float* __restrict__ W2, const float* __restrict__ b2,
    const float* __restrict__ vfold0,
    float* __restrict__ h0, float* __restrict__ asrc, float* __restrict__ adst,
    int n_nodes) {
    __shared__ float W1s[256];
    __shared__ float b1s[32];
    __shared__ float W2s[2048];
    __shared__ float b2s[64];
    __shared__ float vsd[512];
    __shared__ float xS[512];
    __shared__ float h1T[32 * H1STR];
    const int t = threadIdx.x;
    const int n0 = blockIdx.x * 64;
    const int rem = n_nodes - n0;

    *(float4*)(W2s + t * 4) = *(const float4*)(W2 + t * 4);
    *(float4*)(W2s + 1024 + t * 4) = *(const float4*)(W2 + 1024 + t * 4);
    if (t < 64)  *(float4*)(W1s + t * 4) = *(const float4*)(W1 + t * 4);
    if (t < 8)   *(float4*)(b1s + t * 4) = *(const float4*)(b1 + t * 4);
    if (t < 16)  *(float4*)(b2s + t * 4) = *(const float4*)(b2 + t * 4);
    if (t < 128) *(float4*)(vsd + t * 4) = *(const float4*)(vfold0 + t * 4);
    if (t < 128) {
        const int fidx = t * 4;
        float4 v = make_float4(0.f, 0.f, 0.f, 0.f);
        if (fidx < rem * 8) v = *(const float4*)(x + (size_t)n0 * 8 + fidx);
        *(float4*)(xS + fidx) = v;
    }
    __syncthreads();

    {
        const int nl = t >> 2;
        const int j0 = (t & 3) * 8;
        const float4 xa = *(const float4*)(xS + nl * 8);
        const float4 xb = *(const float4*)(xS + nl * 8 + 4);
        const float xk[8] = {xa.x, xa.y, xa.z, xa.w, xb.x, xb.y, xb.z, xb.w};
        float a[8];
#pragma unroll
        for (int u = 0; u < 8; ++u) a[u] = b1s[j0 + u];
#pragma unroll
        for (int k = 0; k < 8; ++k) {
            const float4 w0 = *(const float4*)(W1s + k * 32 + j0);
            const float4 w1 = *(const float4*)(W1s + k * 32 + j0 + 4);
            a[0] += xk[k] * w0.x; a[1] += xk[k] * w0.y;
            a[2] += xk[k] * w0.z; a[3] += xk[k] * w0.w;
            a[4] += xk[k] * w1.x; a[5] += xk[k] * w1.y;
            a[6] += xk[k] * w1.z; a[7] += xk[k] * w1.w;
        }
#pragma unroll
        for (int u = 0; u < 8; ++u) h1T[(j0 + u) * H1STR + nl] = elu_f(a[u]);
    }
    __syncthreads();

    const int cg = t & 15;
    const int nq = t >> 4;
    const int c0 = cg * 4;
    float acc[4][4];
#pragma unroll
    for (int i = 0; i < 4; ++i)
#pragma unroll
        for (int c = 0; c < 4; ++c) acc[i][c] = b2s[c0 + c];
#pragma unroll 8
    for (int k = 0; k < 32; ++k) {
        const float4 hv = *(const float4*)(h1T + k * H1STR + nq * 4);
        const float4 wv = *(const float4*)(W2s + k * 64 + c0);
        const float hvv[4] = {hv.x, hv.y, hv.z, hv.w};
#pragma unroll
        for (int i = 0; i < 4; ++i) {
            acc[i][0] += hvv[i] * wv.x; acc[i][1] += hvv[i] * wv.y;
            acc[i][2] += hvv[i] * wv.z; acc[i][3] += hvv[i] * wv.w;
        }
    }
    float o[4][4];
#pragma unroll
    for (int i = 0; i < 4; ++i)
#pragma unroll
        for (int c = 0; c < 4; ++c) o[i][c] = elu_f(acc[i][c]);

#pragma unroll
    for (int i = 0; i < 4; ++i) {
        const int n = n0 + nq * 4 + i;
        if (n < n_nodes)
            *(float4*)(h0 + (size_t)n * 64 + c0) =
                make_float4(o[i][0], o[i][1], o[i][2], o[i][3]);
    }
    float ad[4][8];
#pragma unroll
    for (int i = 0; i < 4; ++i)
#pragma unroll
        for (int jj = 0; jj < 8; ++jj) ad[i][jj] = 0.f;
#pragma unroll
    for (int c = 0; c < 4; ++c) {
        const float4 v0 = *(const float4*)(vsd + (c0 + c) * 8);
        const float4 v1 = *(const float4*)(vsd + (c0 + c) * 8 + 4);
#pragma unroll
        for (int i = 0; i < 4; ++i) {
            ad[i][0] += o[i][c] * v0.x; ad[i][1] += o[i][c] * v0.y;
            ad[i][2] += o[i][c] * v0.z; ad[i][3] += o[i][c] * v0.w;
            ad[i][4] += o[i][c] * v1.x; ad[i][5] += o[i][c] * v1.y;
            ad[i][6] += o[i][c] * v1.z; ad[i][7] += o[i][c] * v1.w;
        }
    }
#pragma unroll
    for (int off = 1; off < 16; off <<= 1) {
#pragma unroll
        for (int i = 0; i < 4; ++i)
#pragma unroll
            for (int jj = 0; jj < 8; ++jj)
                ad[i][jj] += __shfl_xor(ad[i][jj], off);
    }
    if (cg == 0) {
#pragma unroll
        for (int i = 0; i < 4; ++i) {
            const int n = n0 + nq * 4 + i;
            if (n < n_nodes) {
#pragma unroll
                for (int h = 0; h < 4; ++h) {
                    asrc[n * 4 + h] = ad[i][h];
                    adst[n * 4 + h] = ad[i][4 + h];
                }
            }
        }
    }
}

// ---------------------------------------------------------------------------
// GAT aggregation: one 16-lane group per dst node (4 nodes/wave, 16/block).
// R12 change: 8-unrolled inner loop (8 outstanding dwordx4 gathers per lane
// vs 4) — degree~17 means most groups run one full 16-edge chunk; latency-
// bound, so deeper MLP is the lever. Accumulation order per acc unchanged.
// ---------------------------------------------------------------------------
#define AGG_EDGE(JJ)                                                        \
    {                                                                       \
        const int s = __shfl(c, (JJ), 16);                                  \
        const float4 hv = *(const float4*)(binq + (size_t)s * 64);          \
        const float wx = __shfl(w4.x, (JJ), 16);                            \
        const float wy = __shfl(w4.y, (JJ), 16);                            \
        const float wz = __shfl(w4.z, (JJ), 16);                            \
        const float ww = __shfl(w4.w, (JJ), 16);                            \
        acc[0][0] += wx * hv.x; acc[0][1] += wx * hv.y;                     \
        acc[0][2] += wx * hv.z; acc[0][3] += wx * hv.w;                     \
        acc[1][0] += wy * hv.x; acc[1][1] += wy * hv.y;                     \
        acc[1][2] += wy * hv.z; acc[1][3] += wy * hv.w;                     \
        acc[2][0] += wz * hv.x; acc[2][1] += wz * hv.y;                     \
        acc[2][2] += wz * hv.z; acc[2][3] += wz * hv.w;                     \
        acc[3][0] += ww * hv.x; acc[3][1] += ww * hv.y;                     \
        acc[3][2] += ww * hv.z; acc[3][3] += ww * hv.w;                     \
    }

__global__ __launch_bounds__(256) void gat_agg_kernel(
    const float* __restrict__ bin, const float* __restrict__ asrc,
    const float* __restrict__ adst, const int* __restrict__ rowptr,
    const int* __restrict__ col, float* __restrict__ g, int n_nodes) {
    const int grp = threadIdx.x >> 4;
    const int q = threadIdx.x & 15;
    const int n = blockIdx.x * 16 + grp;
    if (n >= n_nodes) return;
    const float4 ad4 = *(const float4*)(adst + (size_t)n * 4);
    const int start = rowptr[n], end = rowptr[n + 1];
    const float* binq = bin + q * 4;

    float acc[4][4];
#pragma unroll
    for (int h = 0; h < 4; ++h)
#pragma unroll
        for (int z = 0; z < 4; ++z) acc[h][z] = 0.f;
    float4 den4 = make_float4(0.f, 0.f, 0.f, 0.f);

    for (int base = start; base < end; base += 16) {
        const int cnt2 = min(16, end - base);
        int c = 0;
        float4 w4 = make_float4(0.f, 0.f, 0.f, 0.f);
        if (base + q < end) {
            c = col[base + q];
            const float4 av = *(const float4*)(asrc + (size_t)c * 4);
            float l0 = av.x + ad4.x; l0 = l0 > 0.f ? l0 : NEG_SLOPE * l0;
            float l1 = av.y + ad4.y; l1 = l1 > 0.f ? l1 : NEG_SLOPE * l1;
            float l2 = av.z + ad4.z; l2 = l2 > 0.f ? l2 : NEG_SLOPE * l2;
            float l3 = av.w + ad4.w; l3 = l3 > 0.f ? l3 : NEG_SLOPE * l3;
            w4.x = __expf(fminf(l0, 60.f));
            w4.y = __expf(fminf(l1, 60.f));
            w4.z = __expf(fminf(l2, 60.f));
            w4.w = __expf(fminf(l3, 60.f));
            den4.x += w4.x; den4.y += w4.y; den4.z += w4.z; den4.w += w4.w;
        }
        int j = 0;
        for (; j + 8 <= cnt2; j += 8) {
            AGG_EDGE(j + 0); AGG_EDGE(j + 1); AGG_EDGE(j + 2); AGG_EDGE(j + 3);
            AGG_EDGE(j + 4); AGG_EDGE(j + 5); AGG_EDGE(j + 6); AGG_EDGE(j + 7);
        }
        for (; j + 4 <= cnt2; j += 4) {
            AGG_EDGE(j + 0); AGG_EDGE(j + 1); AGG_EDGE(j + 2); AGG_EDGE(j + 3);
        }
        for (; j < cnt2; ++j) {
            AGG_EDGE(j);
        }
    }
#pragma unroll
    for (int off = 1; off < 16; off <<= 1) {
        den4.x += __shfl_xor(den4.x, off, 16);
        den4.y += __shfl_xor(den4.y, off, 16);
        den4.z += __shfl_xor(den4.z, off, 16);
        den4.w += __shfl_xor(den4.w, off, 16);
    }
    const float i0 = 1.f / (den4.x + 1e-16f);
    const float i1 = 1.f / (den4.y + 1e-16f);
    const float i2 = 1.f / (den4.z + 1e-16f);
    const float i3 = 1.f / (den4.w + 1e-16f);
    float* gr = g + (size_t)n * 256 + q * 4;
    *(float4*)(gr +   0) = make_float4(acc[0][0]*i0, acc[0][1]*i0, acc[0][2]*i0, acc[0][3]*i0);
    *(float4*)(gr +  64) = make_float4(acc[1][0]*i1, acc[1][1]*i1, acc[1][2]*i1, acc[1][3]*i1);
    *(float4*)(gr + 128) = make_float4(acc[2][0]*i2, acc[2][1]*i2, acc[2][2]*i2, acc[2][3]*i2);
    *(float4*)(gr + 192) = make_float4(acc[3][0]*i3, acc[3][1]*i3, acc[3][2]*i3, acc[3][3]*i3);
}

// ---------------------------------------------------------------------------
// GAT post-projection. has_next=1: fused next-layer dots. has_next=0: fused
// output MLP 64->64->32->8, writes d_out directly.
// ---------------------------------------------------------------------------
#define GSTR 132
__global__ __launch_bounds__(256) void gat_post_kernel(
    const float* __restrict__ g, const float* __restrict__ W,
    const float* __restrict__ bias, const float* __restrict__ xin,
    const float* __restrict__ vfold_next, int has_next,
    float* __restrict__ out, float* __restrict__ asrc, float* __restrict__ adst,
    const float* __restrict__ Wm1, const float* __restrict__ bm1,
    const float* __restrict__ Wm2, const float* __restrict__ bm2,
    const float* __restrict__ Wm3, const float* __restrict__ bm3,
    float* __restrict__ mlp_out, int n_nodes) {
    __shared__ float gS[64 * GSTR];
    __shared__ float Wp[128 * 64];
    __shared__ float vN[512];
    const int t = threadIdx.x;
    const int n0 = blockIdx.x * 64;
    const int cg = t & 7;
    const int ng = t >> 3;

    if (has_next && t < 128) *(float4*)(vN + t * 4) = *(const float4*)(vfold_next + t * 4);

    float acc[2][8];
#pragma unroll
    for (int i = 0; i < 2; ++i)
#pragma unroll
        for (int qq = 0; qq < 8; ++qq) acc[i][qq] = 0.f;

    for (int slab = 0; slab < 2; ++slab) {
        __syncthreads();
#pragma unroll
        for (int j = 0; j < 8; ++j) {
            const int idx = j * 256 + t;
            const int nl = idx >> 5;
            const int c4 = idx & 31;
            float4 v = make_float4(0.f, 0.f, 0.f, 0.f);
            if (n0 + nl < n_nodes)
                v = *(const float4*)(g + (size_t)(n0 + nl) * 256 + slab * 128 + c4 * 4);
            *(float4*)(gS + nl * GSTR + c4 * 4) = v;
        }
#pragma unroll
        for (int j = 0; j < 8; ++j) {
            const int f4 = j * 256 + t;
            const int kl = f4 >> 4;
            const int kap = slab * 128 + kl;
            const int h = kap >> 6, kk = kap & 63;
            const int c = (f4 & 15) * 4;
            *(float4*)(Wp + kl * 64 + c) = *(const float4*)(W + kk * 256 + h * 64 + c);
        }
        __syncthreads();
#pragma unroll 4
        for (int kl = 0; kl < 128; ++kl) {
            const float a0 = gS[(ng * 2 + 0) * GSTR + kl];
            const float a1 = gS[(ng * 2 + 1) * GSTR + kl];
            const float4 b0 = *(const float4*)(Wp + kl * 64 + cg * 8);
            const float4 b1 = *(const float4*)(Wp + kl * 64 + cg * 8 + 4);
            acc[0][0] += a0 * b0.x; acc[0][1] += a0 * b0.y;
            acc[0][2] += a0 * b0.z; acc[0][3] += a0 * b0.w;
            acc[0][4] += a0 * b1.x; acc[0][5] += a0 * b1.y;
            acc[0][6] += a0 * b1.z; acc[0][7] += a0 * b1.w;
            acc[1][0] += a1 * b0.x; acc[1][1] += a1 * b0.y;
            acc[1][2] += a1 * b0.z; acc[1][3] += a1 * b0.w;
            acc[1][4] += a1 * b1.x; acc[1][5] += a1 * b1.y;
            acc[1][6] += a1 * b1.z; acc[1][7] += a1 * b1.w;
        }
    }

    const int c0 = cg * 8;
    const float4 bb0 = *(const float4*)(bias + c0);
    const float4 bb1 = *(const float4*)(bias + c0 + 4);
    float o[2][8];
#pragma unroll
    for (int i = 0; i < 2; ++i) {
        const int n = n0 + ng * 2 + i;
        if (n < n_nodes) {
            const float4 x0 = *(const float4*)(xin + (size_t)n * 64 + c0);
            const float4 x1 = *(const float4*)(xin + (size_t)n * 64 + c0 + 4);
            o[i][0] = 0.25f * acc[i][0] + bb0.x + x0.x;
            o[i][1] = 0.25f * acc[i][1] + bb0.y + x0.y;
            o[i][2] = 0.25f * acc[i][2] + bb0.z + x0.z;
            o[i][3] = 0.25f * acc[i][3] + bb0.w + x0.w;
            o[i][4] = 0.25f * acc[i][4] + bb1.x + x1.x;
            o[i][5] = 0.25f * acc[i][5] + bb1.y + x1.y;
            o[i][6] = 0.25f * acc[i][6] + bb1.z + x1.z;
            o[i][7] = 0.25f * acc[i][7] + bb1.w + x1.w;
            if (has_next) {
                *(float4*)(out + (size_t)n * 64 + c0) =
                    make_float4(o[i][0], o[i][1], o[i][2], o[i][3]);
                *(float4*)(out + (size_t)n * 64 + c0 + 4) =
                    make_float4(o[i][4], o[i][5], o[i][6], o[i][7]);
            }
        } else {
#pragma unroll
            for (int qq = 0; qq < 8; ++qq) o[i][qq] = 0.f;
        }
    }

    if (has_next) {
        float pj[2][8];
#pragma unroll
        for (int i = 0; i < 2; ++i)
#pragma unroll
            for (int jj = 0; jj < 8; ++jj) pj[i][jj] = 0.f;
#pragma unroll
        for (int cidx = 0; cidx < 8; ++cidx) {
#pragma unroll
            for (int jj = 0; jj < 8; ++jj) {
                const float vv = vN[(c0 + cidx) * 8 + jj];
                pj[0][jj] += o[0][cidx] * vv;
                pj[1][jj] += o[1][cidx] * vv;
            }
        }
#pragma unroll
        for (int off = 1; off < 8; off <<= 1) {
#pragma unroll
            for (int i = 0; i < 2; ++i)
#pragma unroll
                for (int jj = 0; jj < 8; ++jj)
                    pj[i][jj] += __shfl_xor(pj[i][jj], off);
        }
        if (cg == 0) {
#pragma unroll
            for (int i = 0; i < 2; ++i) {
                const int n = n0 + ng * 2 + i;
                if (n < n_nodes) {
#pragma unroll
                    for (int h = 0; h < 4; ++h) {
                        asrc[n * 4 + h] = pj[i][h];
                        adst[n * 4 + h] = pj[i][4 + h];
                    }
                }
            }
        }
        return;
    }

    // ---- fused output MLP (last layer) ----
    __syncthreads();
#pragma unroll
    for (int i = 0; i < 2; ++i) {
        const int nl = ng * 2 + i;
        *(float4*)(gS + nl * GSTR + c0)     = make_float4(o[i][0], o[i][1], o[i][2], o[i][3]);
        *(float4*)(gS + nl * GSTR + c0 + 4) = make_float4(o[i][4], o[i][5], o[i][6], o[i][7]);
    }
    {
#pragma unroll
        for (int j = 0; j < 4; ++j)
            *(float4*)(Wp + (j * 256 + t) * 4) = *(const float4*)(Wm1 + (j * 256 + t) * 4);
#pragma unroll
        for (int j = 0; j < 2; ++j)
            *(float4*)(Wp + 4096 + (j * 256 + t) * 4) = *(const float4*)(Wm2 + (j * 256 + t) * 4);
        if (t < 64) vN[t] = bm1[t];
        else if (t < 96) vN[t] = bm2[t - 64];
        else if (t < 104) vN[t] = bm3[t - 96];
        vN[104 + t] = Wm3[t];
    }
    __syncthreads();
    {
        float a1[2][8];
#pragma unroll
        for (int i = 0; i < 2; ++i)
#pragma unroll
            for (int qq = 0; qq < 8; ++qq) a1[i][qq] = vN[c0 + qq];
#pragma unroll 4
        for (int k = 0; k < 64; ++k) {
            const float h0 = gS[(ng * 2 + 0) * GSTR + k];
            const float h1v = gS[(ng * 2 + 1) * GSTR + k];
            const float4 w0 = *(const float4*)(Wp + k * 64 + c0);
            const float4 w1 = *(const float4*)(Wp + k * 64 + c0 + 4);
            a1[0][0] += h0 * w0.x; a1[0][1] += h0 * w0.y;
            a1[0][2] += h0 * w0.z; a1[0][3] += h0 * w0.w;
            a1[0][4] += h0 * w1.x; a1[0][5] += h0 * w1.y;
            a1[0][6] += h0 * w1.z; a1[0][7] += h0 * w1.w;
            a1[1][0] += h1v * w0.x; a1[1][1] += h1v * w0.y;
            a1[1][2] += h1v * w0.z; a1[1][3] += h1v * w0.w;
            a1[1][4] += h1v * w1.x; a1[1][5] += h1v * w1.y;
            a1[1][6] += h1v * w1.z; a1[1][7] += h1v * w1.w;
        }
#pragma unroll
        for (int i = 0; i < 2; ++i) {
            const int nl = ng * 2 + i;
            float4 v0 = make_float4(elu_f(a1[i][0]), elu_f(a1[i][1]), elu_f(a1[i][2]), elu_f(a1[i][3]));
            float4 v1 = make_float4(elu_f(a1[i][4]), elu_f(a1[i][5]), elu_f(a1[i][6]), elu_f(a1[i][7]));
            *(float4*)(gS + nl * GSTR + 64 + c0)     = v0;
            *(float4*)(gS + nl * GSTR + 64 + c0 + 4) = v1;
        }
    }
    __syncthreads();
    {
        const int cg4 = t & 3;
        const int nn = t >> 2;
        const int cc0 = cg4 * 8;
        float a2[8];
#pragma unroll
        for (int qq = 0; qq < 8; ++qq) a2[qq] = vN[64 + cc0 + qq];
#pragma unroll 4
        for (int j = 0; j < 64; ++j) {
            const float ov = gS[nn * GSTR + 64 + j];
            const float4 w0 = *(const float4*)(Wp + 4096 + j * 32 + cc0);
            const float4 w1 = *(const float4*)(Wp + 4096 + j * 32 + cc0 + 4);
            a2[0] += ov * w0.x; a2[1] += ov * w0.y;
            a2[2] += ov * w0.z; a2[3] += ov * w0.w;
            a2[4] += ov * w1.x; a2[5] += ov * w1.y;
            a2[6] += ov * w1.z; a2[7] += ov * w1.w;
        }
        __syncthreads();
        *(float4*)(gS + nn * GSTR + cc0)     = make_float4(elu_f(a2[0]), elu_f(a2[1]), elu_f(a2[2]), elu_f(a2[3]));
        *(float4*)(gS + nn * GSTR + cc0 + 4) = make_float4(elu_f(a2[4]), elu_f(a2[5]), elu_f(a2[6]), elu_f(a2[7]));
    }
    __syncthreads();
    {
        const int c3 = t & 7;
        const int nq = t >> 3;
#pragma unroll
        for (int i = 0; i < 2; ++i) {
            const int nl = nq * 2 + i;
            const int n = n0 + nl;
            if (n >= n_nodes) continue;
            float a3 = vN[96 + c3];
#pragma unroll 4
            for (int j = 0; j < 32; ++j)
                a3 += gS[nl * GSTR + j] * vN[104 + j * 8 + c3];
            mlp_out[(size_t)n * 8 + c3] = a3;
        }
    }
}

// ---------------------------------------------------------------------------
extern "C" void kernel_launch(void* const* d_in, const int* in_sizes, int n_in,
                              void* d_out, int out_size, void* d_ws, size_t ws_size,
                              hipStream_t stream) {
    const float* x     = (const float*)d_in[0];
    const int*   ei    = (const int*)d_in[1];
    const float* Wenc1 = (const float*)d_in[2];
    const float* benc1 = (const float*)d_in[3];
    const float* Wenc2 = (const float*)d_in[4];
    const float* benc2 = (const float*)d_in[5];
    const float* Wg[3]  = {(const float*)d_in[6],  (const float*)d_in[10], (const float*)d_in[14]};
    const float* as_[3] = {(const float*)d_in[7],  (const float*)d_in[11], (const float*)d_in[15]};
    const float* ad_[3] = {(const float*)d_in[8],  (const float*)d_in[12], (const float*)d_in[16]};
    const float* bg[3]  = {(const float*)d_in[9],  (const float*)d_in[13], (const float*)d_in[17]};
    const float* Wo1 = (const float*)d_in[18];
    const float* bo1 = (const float*)d_in[19];
    const float* Wo2 = (const float*)d_in[20];
    const float* bo2 = (const float*)d_in[21];
    const float* Wo3 = (const float*)d_in[22];
    const float* bo3 = (const float*)d_in[23];

    const int N = in_sizes[0] / 8;
    const int E = in_sizes[1] / 2;
    const int Etot = E + N;
    const int nblk = (N + SCAN_B - 1) / SCAN_B;  // 79

    float* buf0  = (float*)d_ws;                  // N*64
    float* buf1  = buf0 + (size_t)N * 64;         // N*64
    float* g     = buf1 + (size_t)N * 64;         // N*256
    float* asrc  = g + (size_t)N * 256;           // N*4
    float* adst  = asrc + (size_t)N * 4;          // N*4
    float* vfold = adst + (size_t)N * 4;          // 3*512
    int* rowptr = (int*)(vfold + 3 * 512);        // N+1 (+pad)
    int* cursor = rowptr + (N + 2);               // N
    int* cnt    = cursor + N;                     // N
    int* ready  = cnt + N;                        // 128
    int* flag   = ready + 128;                    // 1 (+pad)
    int* col    = flag + 2;                       // Etot

    prep_kernel<<<nblk + 6, 256, 0, stream>>>(ei,
        Wg[0], as_[0], ad_[0], Wg[1], as_[1], ad_[1], Wg[2], as_[2], ad_[2],
        cnt, ready, flag, vfold, N);
    count_kernel<<<(Etot + 255) / 256, 256, 0, stream>>>(ei, flag, E, Etot, cnt);
    scan_onepass_kernel<<<nblk, SCAN_B, 0, stream>>>(cnt, ready, rowptr, cursor, N);
    fill_kernel<<<(Etot + 255) / 256, 256, 0, stream>>>(ei, flag, E, Etot, cursor, col);

    encoder_kernel<<<(N + 63) / 64, 256, 0, stream>>>(x, Wenc1, benc1, Wenc2, benc2,
                                                      vfold, buf0, asrc, adst, N);

    float* bin = buf0;
    float* bout = buf1;
    for (int l = 0; l < 3; ++l) {
        gat_agg_kernel<<<(N + 15) / 16, 256, 0, stream>>>(bin, asrc, adst, rowptr, col,
                                                          g, N);
        const int has_next = (l < 2) ? 1 : 0;
        gat_post_kernel<<<(N + 63) / 64, 256, 0, stream>>>(
            g, Wg[l], bg[l], bin, vfold + (l + 1 < 3 ? (l + 1) * 512 : 0), has_next,
            bout, asrc, adst,
            Wo1, bo1, Wo2, bo2, Wo3, bo3, (float*)d_out, N);
        float* tmp = bin; bin = bout; bout = tmp;
    }
}